// Round 2
// baseline (556.006 us; speedup 1.0000x reference)
//
#include <hip/hip_runtime.h>
#include <math.h>

// RBFController: B=2048, N=32 centers, D=64 dims, A=8 actions.
// One 256-thread block per batch element, 4 blocks/CU (LDS ~35 KB).
// Two SPD 64x64 LDL^T factorizations done sequentially into ONE shared L^T
// buffer via wave-local blocked-panel factorization (shfl-only panels,
// 4 barriers/matrix). Wave-synchronous triangular solves.

#define DD 64
#define NN 32
#define AA 8
#define NBATCH 2048
#define STR 68   // L^T / H row stride (words): 272 B, 16B-aligned rows
#define W9 9     // padded stride for N x A / D x A arrays (kills 8/16-way conflicts)

// ---------------- prep: exp1[n][m] table + logdet_lh scalar ----------------
__global__ void rbf_prep(const float* __restrict__ centers,
                         const float* __restrict__ ls,
                         float* __restrict__ ws) {
    __shared__ float cen_s[NN * DD];
    __shared__ float il2_s[DD];
    int t = threadIdx.x;
    for (int e = t; e < NN * DD; e += 256) cen_s[e] = centers[e];
    if (t < DD) { float l = ls[t]; il2_s[t] = 1.0f / (l * l); }
    __syncthreads();
    int p = blockIdx.x * 256 + t;
    if (p < NN * NN) {
        int n = p >> 5, m = p & 31;
        float acc = 0.f;
        for (int d = 0; d < DD; ++d) {
            float df = cen_s[n * DD + d] - cen_s[m * DD + d];
            acc += df * df * il2_s[d];
        }
        ws[p] = -0.25f * acc;              // exp1[n][m]
    }
    if (blockIdx.x == 0 && t < DD) {
        float l = ls[t];
        float v = logf(0.5f * l * l);
        #pragma unroll
        for (int o = 1; o < 64; o <<= 1) v += __shfl_xor(v, o, 64);
        if (t == 0) ws[NN * NN] = v;       // logdet_lh
    }
}

// Wave-local panel factorization: wave owns cols 16p..16p+15 of A in its
// register tiles (lane lw: rows 4*(lw&15).., cols 16p+4*(lw>>4)..). Pure
// shfl pivot-column exchange; writes zero-filled L^T rows to LDS.
__device__ __forceinline__ void factor_panel(float (&A)[4][4], const int p,
    float* __restrict__ LmT, float* __restrict__ diag_s, float* __restrict__ invd_s,
    const int lw)
{
    const int rb  = lw & 15;
    const int cbl = lw >> 4;               // 0..3 (panel-local col tile)
    const int c0  = 16 * p + 4 * cbl;
    const int r0  = 4 * rb;
    #pragma unroll
    for (int jj = 0; jj < 16; ++jj) {
        const int q  = jj >> 2;
        const int ci = jj & 3;
        const int j  = 16 * p + jj;
        const int fsrc = rb | (q << 4);               // same row-tile, owner col-tile
        const int hsrc = (4 * p + cbl) | (q << 4);    // row-tile = my col range
        const int dsrc = (4 * p + q) | (q << 4);      // pivot element owner
        float d  = __shfl(A[ci][ci], dsrc, 64);
        float f0 = __shfl(A[0][ci], fsrc, 64);
        float f1 = __shfl(A[1][ci], fsrc, 64);
        float f2 = __shfl(A[2][ci], fsrc, 64);
        float f3 = __shfl(A[3][ci], fsrc, 64);
        float h0 = __shfl(A[0][ci], hsrc, 64);
        float h1 = __shfl(A[1][ci], hsrc, 64);
        float h2 = __shfl(A[2][ci], hsrc, 64);
        float h3 = __shfl(A[3][ci], hsrc, 64);
        float id = __builtin_amdgcn_rcpf(d);   // cond(A) ~ 1; ~1ulp fine
        float fr[4];
        fr[0] = (r0 + 0 > j) ? f0 : 0.f;
        fr[1] = (r0 + 1 > j) ? f1 : 0.f;
        fr[2] = (r0 + 2 > j) ? f2 : 0.f;
        fr[3] = (r0 + 3 > j) ? f3 : 0.f;
        float hc[4];
        hc[0] = (c0 + 0 > j) ? h0 * id : 0.f;
        hc[1] = (c0 + 1 > j) ? h1 * id : 0.f;
        hc[2] = (c0 + 2 > j) ? h2 * id : 0.f;
        hc[3] = (c0 + 3 > j) ? h3 * id : 0.f;
        #pragma unroll
        for (int s = 0; s < 4; ++s)
            #pragma unroll
            for (int c = 0; c < 4; ++c)
                A[s][c] -= fr[s] * hc[c];
        if (cbl == 0) {   // 16 lanes write full zero-filled L^T row j
            float4 v = make_float4(fr[0] * id, fr[1] * id, fr[2] * id, fr[3] * id);
            *(float4*)&LmT[j * STR + r0] = v;
        }
        if (lw == jj) { diag_s[j] = d; invd_s[j] = id; }
    }
}

// Rank-16 trailing update from panel p. Zero-filled L^T rows auto-mask
// rows<=k and cols<=k — unpredicated.
__device__ __forceinline__ void trailing_update(float (&A)[4][4], const int p,
    const float* __restrict__ LmT, const float* __restrict__ diag_s,
    const int rb, const int cb)
{
    #pragma unroll
    for (int kk = 0; kk < 16; ++kk) {
        const int k = 16 * p + kk;
        const float4 Lr = *(const float4*)&LmT[k * STR + 4 * rb];
        const float4 Lc = *(const float4*)&LmT[k * STR + 4 * cb];
        const float dk = diag_s[k];
        const float hc0 = Lc.x * dk, hc1 = Lc.y * dk, hc2 = Lc.z * dk, hc3 = Lc.w * dk;
        A[0][0] -= Lr.x * hc0; A[0][1] -= Lr.x * hc1; A[0][2] -= Lr.x * hc2; A[0][3] -= Lr.x * hc3;
        A[1][0] -= Lr.y * hc0; A[1][1] -= Lr.y * hc1; A[1][2] -= Lr.y * hc2; A[1][3] -= Lr.y * hc3;
        A[2][0] -= Lr.z * hc0; A[2][1] -= Lr.z * hc1; A[2][2] -= Lr.z * hc2; A[2][3] -= Lr.z * hc3;
        A[3][0] -= Lr.w * hc0; A[3][1] -= Lr.w * hc1; A[3][2] -= Lr.w * hc2; A[3][3] -= Lr.w * hc3;
    }
}

__global__ __launch_bounds__(256, 4) void rbf_main(
    const float* __restrict__ mean,      // (B,64)
    const float* __restrict__ cov,       // (B,64,64)
    const float* __restrict__ centers,   // (32,64)
    const float* __restrict__ weights,   // (32,8)
    const float* __restrict__ ls,        // (64,)
    const float* __restrict__ ws,        // exp1[1024], logdet_lh at [1024]
    float* __restrict__ out)
{
    __shared__ __align__(16) float LmT[DD * STR];   // 17408 B (L2^T then L1^T)
    __shared__ __align__(16) float H_s[NN * STR];   // 8704 B
    __shared__ __align__(16) float K_s[DD * W9];    // 2304 B
    __shared__ __align__(16) float cp_s[DD * W9];   // 2304 B
    __shared__ float diag_s[DD], invd_s[DD];
    __shared__ float mean_s[DD], invl_s[DD], l2h_s[DD];
    __shared__ float w9_s[NN * W9], phiw_s[NN * W9], U_s[NN * W9];
    __shared__ float am_s[AA], acr_s[AA * W9], Ca_s[AA];
    __shared__ float ldlh_s;

    const int t   = threadIdx.x;
    const int b   = blockIdx.x;
    const int lw  = t & 63;
    const int wv  = t >> 6;
    const int rb  = t & 15;   // row tile (rows 4rb..4rb+3)
    const int cb  = t >> 4;   // col tile (cols 4cb..4cb+3); wave w owns cols 16w..16w+15
    const int grp = t >> 3;   // RHS group 0..31 in solves
    const int l8  = t & 7;    // lane-in-group (rows 8*l8..8*l8+7)

    // ---- stage small arrays ----
    if (t < DD) {
        float l = ls[t];
        invl_s[t] = 1.0f / l;
        l2h_s[t]  = 0.5f * l * l;
        mean_s[t] = mean[(size_t)b * DD + t];
    }
    w9_s[(t >> 3) * W9 + (t & 7)] = weights[t];
    if (t == 0) ldlh_s = ws[NN * NN];
    __syncthreads();

    // ---- build A1 = Dl cov Dl + I and A2 = cov + diag(l^2/2) ----
    // tile(rb,cb) loaded via symmetry from rows 4cb..4cb+3 (coalesced)
    float A1[4][4], A2[4][4];
    {
        const float* cvb = cov + (size_t)b * DD * DD;
        const float il0 = invl_s[4*rb+0], il1 = invl_s[4*rb+1],
                    il2 = invl_s[4*rb+2], il3 = invl_s[4*rb+3];
        #pragma unroll
        for (int c = 0; c < 4; ++c) {
            const int gr = 4 * cb + c;
            const float4 cv = *(const float4*)(cvb + (size_t)gr * DD + 4 * rb);
            const float ilc = invl_s[gr];
            A1[0][c] = cv.x * il0 * ilc + ((4*rb+0 == gr) ? 1.0f : 0.0f);
            A1[1][c] = cv.y * il1 * ilc + ((4*rb+1 == gr) ? 1.0f : 0.0f);
            A1[2][c] = cv.z * il2 * ilc + ((4*rb+2 == gr) ? 1.0f : 0.0f);
            A1[3][c] = cv.w * il3 * ilc + ((4*rb+3 == gr) ? 1.0f : 0.0f);
            A2[0][c] = cv.x + ((4*rb+0 == gr) ? l2h_s[gr] : 0.0f);
            A2[1][c] = cv.y + ((4*rb+1 == gr) ? l2h_s[gr] : 0.0f);
            A2[2][c] = cv.z + ((4*rb+2 == gr) ? l2h_s[gr] : 0.0f);
            A2[3][c] = cv.w + ((4*rb+3 == gr) ? l2h_s[gr] : 0.0f);
        }
    }

    // ---- factor M2 = B_q (look-ahead: wave p+1 trails then factors) ----
    if (wv == 0) factor_panel(A2, 0, LmT, diag_s, invd_s, lw);
    #pragma unroll 1
    for (int p = 0; p < 3; ++p) {
        __syncthreads();
        trailing_update(A2, p, LmT, diag_s, rb, cb);
        if (wv == p + 1) factor_panel(A2, p + 1, LmT, diag_s, invd_s, lw);
    }
    __syncthreads();

    // per-wave (redundant) logdet2 -> cq; avoids extra barrier
    float cq;
    {
        float v = logf(diag_s[lw]);
        #pragma unroll
        for (int o = 1; o < 64; o <<= 1) v += __shfl_xor(v, o, 64);
        cq = expf(0.5f * (ldlh_s - v));
    }

    // ---- forward solve M2 (32 RHS): H = D^{-1/2} L2^{-1} (c_n - mean)/2 ----
    {
        float x[8];
        const float4 ca = *(const float4*)(centers + grp * DD + 8 * l8);
        const float4 cb4 = *(const float4*)(centers + grp * DD + 8 * l8 + 4);
        x[0] = 0.5f * (ca.x  - mean_s[8*l8+0]);
        x[1] = 0.5f * (ca.y  - mean_s[8*l8+1]);
        x[2] = 0.5f * (ca.z  - mean_s[8*l8+2]);
        x[3] = 0.5f * (ca.w  - mean_s[8*l8+3]);
        x[4] = 0.5f * (cb4.x - mean_s[8*l8+4]);
        x[5] = 0.5f * (cb4.y - mean_s[8*l8+5]);
        x[6] = 0.5f * (cb4.z - mean_s[8*l8+6]);
        x[7] = 0.5f * (cb4.w - mean_s[8*l8+7]);
        for (int k8 = 0; k8 < 8; ++k8) {
            #pragma unroll
            for (int kk = 0; kk < 8; ++kk) {
                int k = 8 * k8 + kk;
                float zk = __shfl(x[kk], (lw & 56) | k8, 64);
                #pragma unroll
                for (int s = 0; s < 8; ++s)
                    x[s] -= LmT[k * STR + 8 * l8 + s] * zk;   // zero-filled rows
            }
        }
        #pragma unroll
        for (int s = 0; s < 8; ++s)
            H_s[grp * STR + 8 * l8 + s] = x[s] * sqrtf(invd_s[8 * l8 + s]);
    }
    __syncthreads();

    // ---- M1 panel 0 (wave 0) overlapped with Gram/Q/U (all waves) ----
    if (wv == 0) factor_panel(A1, 0, LmT, diag_s, invd_s, lw);
    {
        float acc[4] = {0.f, 0.f, 0.f, 0.f};
        const int rot = 2 * l8;   // per-lane column rotation: kills bank conflicts
        #pragma unroll
        for (int e = 0; e < 16; ++e) {
            const int e4 = 4 * ((e + rot) & 15);
            const float4 hn = *(const float4*)&H_s[grp * STR + e4];
            #pragma unroll
            for (int mm = 0; mm < 4; ++mm) {
                const float4 hm = *(const float4*)&H_s[(4 * l8 + mm) * STR + e4];
                float s0 = hn.x + hm.x, s1 = hn.y + hm.y;
                float s2 = hn.z + hm.z, s3 = hn.w + hm.w;
                acc[mm] += s0*s0 + s1*s1 + s2*s2 + s3*s3;   // |h_n+h_m|^2
            }
        }
        const float4 e1 = *(const float4*)&ws[grp * NN + 4 * l8];
        float Q0 = cq * expf(e1.x - 0.5f * acc[0]);
        float Q1 = cq * expf(e1.y - 0.5f * acc[1]);
        float Q2 = cq * expf(e1.z - 0.5f * acc[2]);
        float Q3 = cq * expf(e1.w - 0.5f * acc[3]);
        float u[8];
        #pragma unroll
        for (int a = 0; a < 8; ++a) {
            u[a] = Q0 * w9_s[(4*l8+0)*W9 + a] + Q1 * w9_s[(4*l8+1)*W9 + a]
                 + Q2 * w9_s[(4*l8+2)*W9 + a] + Q3 * w9_s[(4*l8+3)*W9 + a];
            u[a] += __shfl_xor(u[a], 1, 64);
            u[a] += __shfl_xor(u[a], 2, 64);
            u[a] += __shfl_xor(u[a], 4, 64);
        }
        float uv = (l8 == 0) ? u[0] : (l8 == 1) ? u[1] : (l8 == 2) ? u[2] : (l8 == 3) ? u[3]
                 : (l8 == 4) ? u[4] : (l8 == 5) ? u[5] : (l8 == 6) ? u[6] : u[7];
        U_s[grp * W9 + l8] = uv;   // U = Q w
    }
    #pragma unroll 1
    for (int p = 0; p < 3; ++p) {
        __syncthreads();
        trailing_update(A1, p, LmT, diag_s, rb, cb);
        if (wv == p + 1) factor_panel(A1, p + 1, LmT, diag_s, invd_s, lw);
    }
    __syncthreads();

    // per-wave logdet1
    float logdet1;
    {
        float v = logf(diag_s[lw]);
        #pragma unroll
        for (int o = 1; o < 64; o <<= 1) v += __shfl_xor(v, o, 64);
        logdet1 = v;
    }

    // ---- forward solve M1 (32 RHS) -> phi, phiw ----
    {
        float x[8];
        const float4 ca = *(const float4*)(centers + grp * DD + 8 * l8);
        const float4 cb4 = *(const float4*)(centers + grp * DD + 8 * l8 + 4);
        x[0] = (ca.x  - mean_s[8*l8+0]) * invl_s[8*l8+0];
        x[1] = (ca.y  - mean_s[8*l8+1]) * invl_s[8*l8+1];
        x[2] = (ca.z  - mean_s[8*l8+2]) * invl_s[8*l8+2];
        x[3] = (ca.w  - mean_s[8*l8+3]) * invl_s[8*l8+3];
        x[4] = (cb4.x - mean_s[8*l8+4]) * invl_s[8*l8+4];
        x[5] = (cb4.y - mean_s[8*l8+5]) * invl_s[8*l8+5];
        x[6] = (cb4.z - mean_s[8*l8+6]) * invl_s[8*l8+6];
        x[7] = (cb4.w - mean_s[8*l8+7]) * invl_s[8*l8+7];
        for (int k8 = 0; k8 < 8; ++k8) {
            #pragma unroll
            for (int kk = 0; kk < 8; ++kk) {
                int k = 8 * k8 + kk;
                float zk = __shfl(x[kk], (lw & 56) | k8, 64);
                #pragma unroll
                for (int s = 0; s < 8; ++s)
                    x[s] -= LmT[k * STR + 8 * l8 + s] * zk;
            }
        }
        float qf = 0.f;
        #pragma unroll
        for (int s = 0; s < 8; ++s) qf += x[s] * x[s] * invd_s[8 * l8 + s];
        qf += __shfl_xor(qf, 1, 64);
        qf += __shfl_xor(qf, 2, 64);
        qf += __shfl_xor(qf, 4, 64);
        float ph = expf(-0.5f * (logdet1 + qf));   // normalizer * exp_term
        phiw_s[grp * W9 + l8] = ph * w9_s[grp * W9 + l8];
    }
    __syncthreads();

    // ---- K[d][a] = sum_n s_n[d] * phiw[n][a] (centers from L1/L2) ----
    {
        const int d = t >> 2, a0 = (t & 3) * 2;
        const float md = mean_s[d], il = invl_s[d];
        float k0 = 0.f, k1 = 0.f;
        for (int n = 0; n < NN; ++n) {
            float sv = (centers[n * DD + d] - md) * il;
            k0 += sv * phiw_s[n * W9 + a0];
            k1 += sv * phiw_s[n * W9 + a0 + 1];
        }
        K_s[d * W9 + a0]     = k0;
        K_s[d * W9 + a0 + 1] = k1;
    }
    __syncthreads();

    // ---- parallel: wave0 solve B1^{-1}K (8 RHS) | amean | acr = w^T U ----
    if (t < 64) {
        const int aa = t >> 3;   // RHS index
        float y[8];
        #pragma unroll
        for (int s = 0; s < 8; ++s) y[s] = K_s[(8 * l8 + s) * W9 + aa];
        for (int k8 = 0; k8 < 8; ++k8) {              // forward (unit-L)
            #pragma unroll
            for (int kk = 0; kk < 8; ++kk) {
                int k = 8 * k8 + kk;
                float zk = __shfl(y[kk], (t & 56) | k8, 64);
                #pragma unroll
                for (int s = 0; s < 8; ++s)
                    y[s] -= LmT[k * STR + 8 * l8 + s] * zk;
            }
        }
        #pragma unroll
        for (int s = 0; s < 8; ++s) y[s] *= invd_s[8 * l8 + s];
        // backward (L^T), dot-form: reads L^T ROWS (contiguous, conflict-free);
        // zero-filled entries auto-mask k<=i.
        for (int i8 = 7; i8 >= 0; --i8) {
            #pragma unroll
            for (int ii = 7; ii >= 0; --ii) {
                const int i = 8 * i8 + ii;
                const float4 r0 = *(const float4*)&LmT[i * STR + 8 * l8];
                const float4 r1 = *(const float4*)&LmT[i * STR + 8 * l8 + 4];
                float part = r0.x*y[0] + r0.y*y[1] + r0.z*y[2] + r0.w*y[3]
                           + r1.x*y[4] + r1.y*y[5] + r1.z*y[6] + r1.w*y[7];
                part += __shfl_xor(part, 1, 64);
                part += __shfl_xor(part, 2, 64);
                part += __shfl_xor(part, 4, 64);
                if (l8 == i8) y[ii] -= part;
            }
        }
        #pragma unroll
        for (int s = 0; s < 8; ++s)
            cp_s[(8 * l8 + s) * W9 + aa] = y[s] * invl_s[8 * l8 + s];
    } else if (t < 72) {
        int a = t - 64;
        float am = 0.f;
        for (int n = 0; n < NN; ++n) am += phiw_s[n * W9 + a];
        am_s[a] = am;
    } else if (t >= 128 && t < 192) {
        int t2 = t - 128, a = t2 >> 3, c = t2 & 7;
        float acc2 = 0.f;
        for (int n = 0; n < NN; ++n) acc2 += w9_s[n * W9 + a] * U_s[n * W9 + c];
        acr_s[a * W9 + c] = acc2;
    }
    __syncthreads();

    // ---- squash + outputs ----
    float* out0 = out;
    float* out1 = out + (size_t)NBATCH * AA;
    float* out2 = out + (size_t)NBATCH * AA + (size_t)NBATCH * AA * AA;
    if (t < 64) {
        const int a = t >> 3, c = t & 7;
        const float ama = am_s[a], amc = am_s[c];
        const float vac = 0.5f * (acr_s[a * W9 + c] + acr_s[c * W9 + a])
                        - ama * amc + ((a == c) ? 1e-6f : 0.0f);
        const float dca = acr_s[a * W9 + a] - ama * ama + 1e-6f;
        const float dcc = acr_s[c * W9 + c] - amc * amc + 1e-6f;
        const float q = expf(-0.5f * (dca + dcc));
        // expm1 formulation avoids catastrophic cancellation at vac ~ 1e-6
        const float sq = 0.5f * q * (expm1f(vac) * cosf(ama - amc)
                                   - expm1f(-vac) * cosf(ama + amc));
        out1[(size_t)b * 64 + t] = sq;
        if (t < AA) {
            float dct = acr_s[t * W9 + t] - am_s[t] * am_s[t] + 1e-6f;
            float e = expf(-0.5f * dct);
            out0[(size_t)b * AA + t] = e * sinf(am_s[t]);
            Ca_s[t] = e * cosf(am_s[t]);
        }
    }
    __syncthreads();
    #pragma unroll
    for (int e = 0; e < 2; ++e) {
        int idx = t + 256 * e;
        out2[(size_t)b * 512 + idx] = cp_s[(idx >> 3) * W9 + (idx & 7)] * Ca_s[idx & 7];
    }
}

extern "C" void kernel_launch(void* const* d_in, const int* in_sizes, int n_in,
                              void* d_out, int out_size, void* d_ws, size_t ws_size,
                              hipStream_t stream) {
    (void)in_sizes; (void)n_in; (void)out_size; (void)ws_size;
    const float* mean    = (const float*)d_in[0];
    const float* cov     = (const float*)d_in[1];
    const float* centers = (const float*)d_in[2];
    const float* weights = (const float*)d_in[3];
    const float* ls      = (const float*)d_in[4];
    float* ws = (float*)d_ws;
    float* o  = (float*)d_out;
    rbf_prep<<<4, 256, 0, stream>>>(centers, ls, ws);
    rbf_main<<<NBATCH, 256, 0, stream>>>(mean, cov, centers, weights, ls, ws, o);
}

// Round 3
// 488.253 us; speedup vs baseline: 1.1388x; 1.1388x over previous
//
#include <hip/hip_runtime.h>
#include <math.h>

// RBFController: B=2048, N=32 centers, D=64 dims, A=8 actions.
// One 256-thread block per batch element, 4 blocks/CU (LDS ~35 KB).
// Two SPD 64x64 LDL^T factorizations done SEQUENTIALLY (A2 then A1, A1 tile
// built late from an L2-resident cov re-read to keep only ONE 4x4 register
// tile live at a time -> no spills). Wave-local blocked-panel factorization
// (shfl-only panels, 4 barriers/matrix), wave-synchronous triangular solves.
// NOTE: no __launch_bounds__ min-waves arg — round 2 showed (256,4) clamps
// VGPRs to 64 and generates ~900 MB/launch of scratch spill traffic.

#define DD 64
#define NN 32
#define AA 8
#define NBATCH 2048
#define STR 68   // L^T / H row stride (words): 272 B, 16B-aligned rows
#define W9 9     // padded stride for N x A / D x A arrays (kills 8/16-way conflicts)

// ---------------- prep: exp1[n][m] table + logdet_lh scalar ----------------
__global__ void rbf_prep(const float* __restrict__ centers,
                         const float* __restrict__ ls,
                         float* __restrict__ ws) {
    __shared__ float cen_s[NN * DD];
    __shared__ float il2_s[DD];
    int t = threadIdx.x;
    for (int e = t; e < NN * DD; e += 256) cen_s[e] = centers[e];
    if (t < DD) { float l = ls[t]; il2_s[t] = 1.0f / (l * l); }
    __syncthreads();
    int p = blockIdx.x * 256 + t;
    if (p < NN * NN) {
        int n = p >> 5, m = p & 31;
        float acc = 0.f;
        for (int d = 0; d < DD; ++d) {
            float df = cen_s[n * DD + d] - cen_s[m * DD + d];
            acc += df * df * il2_s[d];
        }
        ws[p] = -0.25f * acc;              // exp1[n][m]
    }
    if (blockIdx.x == 0 && t < DD) {
        float l = ls[t];
        float v = logf(0.5f * l * l);
        #pragma unroll
        for (int o = 1; o < 64; o <<= 1) v += __shfl_xor(v, o, 64);
        if (t == 0) ws[NN * NN] = v;       // logdet_lh
    }
}

// Wave-local panel factorization: wave owns cols 16p..16p+15 of A in its
// register tiles (lane lw: rows 4*(lw&15).., cols 16p+4*(lw>>4)..). Pure
// shfl pivot-column exchange; writes zero-filled L^T rows to LDS.
__device__ __forceinline__ void factor_panel(float (&A)[4][4], const int p,
    float* __restrict__ LmT, float* __restrict__ diag_s, float* __restrict__ invd_s,
    const int lw)
{
    const int rb  = lw & 15;
    const int cbl = lw >> 4;               // 0..3 (panel-local col tile)
    const int c0  = 16 * p + 4 * cbl;
    const int r0  = 4 * rb;
    #pragma unroll
    for (int jj = 0; jj < 16; ++jj) {
        const int q  = jj >> 2;
        const int ci = jj & 3;
        const int j  = 16 * p + jj;
        const int fsrc = rb | (q << 4);               // same row-tile, owner col-tile
        const int hsrc = (4 * p + cbl) | (q << 4);    // row-tile = my col range
        const int dsrc = (4 * p + q) | (q << 4);      // pivot element owner
        float d  = __shfl(A[ci][ci], dsrc, 64);
        float f0 = __shfl(A[0][ci], fsrc, 64);
        float f1 = __shfl(A[1][ci], fsrc, 64);
        float f2 = __shfl(A[2][ci], fsrc, 64);
        float f3 = __shfl(A[3][ci], fsrc, 64);
        float h0 = __shfl(A[0][ci], hsrc, 64);
        float h1 = __shfl(A[1][ci], hsrc, 64);
        float h2 = __shfl(A[2][ci], hsrc, 64);
        float h3 = __shfl(A[3][ci], hsrc, 64);
        float id = __builtin_amdgcn_rcpf(d);   // cond(A) ~ 1; ~1ulp fine
        float fr[4];
        fr[0] = (r0 + 0 > j) ? f0 : 0.f;
        fr[1] = (r0 + 1 > j) ? f1 : 0.f;
        fr[2] = (r0 + 2 > j) ? f2 : 0.f;
        fr[3] = (r0 + 3 > j) ? f3 : 0.f;
        float hc[4];
        hc[0] = (c0 + 0 > j) ? h0 * id : 0.f;
        hc[1] = (c0 + 1 > j) ? h1 * id : 0.f;
        hc[2] = (c0 + 2 > j) ? h2 * id : 0.f;
        hc[3] = (c0 + 3 > j) ? h3 * id : 0.f;
        #pragma unroll
        for (int s = 0; s < 4; ++s)
            #pragma unroll
            for (int c = 0; c < 4; ++c)
                A[s][c] -= fr[s] * hc[c];
        if (cbl == 0) {   // 16 lanes write full zero-filled L^T row j
            float4 v = make_float4(fr[0] * id, fr[1] * id, fr[2] * id, fr[3] * id);
            *(float4*)&LmT[j * STR + r0] = v;
        }
        if (lw == jj) { diag_s[j] = d; invd_s[j] = id; }
    }
}

// Rank-16 trailing update from panel p. Zero-filled L^T rows auto-mask
// rows<=k and cols<=k — unpredicated.
__device__ __forceinline__ void trailing_update(float (&A)[4][4], const int p,
    const float* __restrict__ LmT, const float* __restrict__ diag_s,
    const int rb, const int cb)
{
    #pragma unroll
    for (int kk = 0; kk < 16; ++kk) {
        const int k = 16 * p + kk;
        const float4 Lr = *(const float4*)&LmT[k * STR + 4 * rb];
        const float4 Lc = *(const float4*)&LmT[k * STR + 4 * cb];
        const float dk = diag_s[k];
        const float hc0 = Lc.x * dk, hc1 = Lc.y * dk, hc2 = Lc.z * dk, hc3 = Lc.w * dk;
        A[0][0] -= Lr.x * hc0; A[0][1] -= Lr.x * hc1; A[0][2] -= Lr.x * hc2; A[0][3] -= Lr.x * hc3;
        A[1][0] -= Lr.y * hc0; A[1][1] -= Lr.y * hc1; A[1][2] -= Lr.y * hc2; A[1][3] -= Lr.y * hc3;
        A[2][0] -= Lr.z * hc0; A[2][1] -= Lr.z * hc1; A[2][2] -= Lr.z * hc2; A[2][3] -= Lr.z * hc3;
        A[3][0] -= Lr.w * hc0; A[3][1] -= Lr.w * hc1; A[3][2] -= Lr.w * hc2; A[3][3] -= Lr.w * hc3;
    }
}

__global__ __launch_bounds__(256) void rbf_main(
    const float* __restrict__ mean,      // (B,64)
    const float* __restrict__ cov,       // (B,64,64)
    const float* __restrict__ centers,   // (32,64)
    const float* __restrict__ weights,   // (32,8)
    const float* __restrict__ ls,        // (64,)
    const float* __restrict__ ws,        // exp1[1024], logdet_lh at [1024]
    float* __restrict__ out)
{
    __shared__ __align__(16) float LmT[DD * STR];   // 17408 B (L2^T then L1^T)
    __shared__ __align__(16) float H_s[NN * STR];   // 8704 B
    __shared__ __align__(16) float K_s[DD * W9];    // 2304 B
    __shared__ __align__(16) float cp_s[DD * W9];   // 2304 B
    __shared__ float diag_s[DD], invd_s[DD];
    __shared__ float mean_s[DD], invl_s[DD], l2h_s[DD];
    __shared__ float w9_s[NN * W9], phiw_s[NN * W9], U_s[NN * W9];
    __shared__ float am_s[AA], acr_s[AA * W9], Ca_s[AA];
    __shared__ float ldlh_s;

    const int t   = threadIdx.x;
    const int b   = blockIdx.x;
    const int lw  = t & 63;
    const int wv  = t >> 6;
    const int rb  = t & 15;   // row tile (rows 4rb..4rb+3)
    const int cb  = t >> 4;   // col tile (cols 4cb..4cb+3); wave w owns cols 16w..16w+15
    const int grp = t >> 3;   // RHS group 0..31 in solves
    const int l8  = t & 7;    // lane-in-group (rows 8*l8..8*l8+7)
    const float* cvb = cov + (size_t)b * DD * DD;

    // ---- stage small arrays ----
    if (t < DD) {
        float l = ls[t];
        invl_s[t] = 1.0f / l;
        l2h_s[t]  = 0.5f * l * l;
        mean_s[t] = mean[(size_t)b * DD + t];
    }
    w9_s[(t >> 3) * W9 + (t & 7)] = weights[t];
    if (t == 0) ldlh_s = ws[NN * NN];
    __syncthreads();

    // ================= PHASE 1: M2 = cov + diag(l^2/2) =================
    {
        float A2[4][4];
        #pragma unroll
        for (int c = 0; c < 4; ++c) {
            const int gr = 4 * cb + c;   // symmetric load: read rows 4cb.. (coalesced)
            const float4 cv = *(const float4*)(cvb + (size_t)gr * DD + 4 * rb);
            A2[0][c] = cv.x + ((4*rb+0 == gr) ? l2h_s[gr] : 0.0f);
            A2[1][c] = cv.y + ((4*rb+1 == gr) ? l2h_s[gr] : 0.0f);
            A2[2][c] = cv.z + ((4*rb+2 == gr) ? l2h_s[gr] : 0.0f);
            A2[3][c] = cv.w + ((4*rb+3 == gr) ? l2h_s[gr] : 0.0f);
        }
        if (wv == 0) factor_panel(A2, 0, LmT, diag_s, invd_s, lw);
        #pragma unroll 1
        for (int p = 0; p < 3; ++p) {
            __syncthreads();
            trailing_update(A2, p, LmT, diag_s, rb, cb);
            if (wv == p + 1) factor_panel(A2, p + 1, LmT, diag_s, invd_s, lw);
        }
        __syncthreads();
    }

    // per-wave (redundant) logdet2 -> cq; avoids extra barrier
    float cq;
    {
        float v = logf(diag_s[lw]);
        #pragma unroll
        for (int o = 1; o < 64; o <<= 1) v += __shfl_xor(v, o, 64);
        cq = expf(0.5f * (ldlh_s - v));
    }

    // ---- forward solve M2 (32 RHS): H = D^{-1/2} L2^{-1} (c_n - mean)/2 ----
    {
        float x[8];
        const float4 ca  = *(const float4*)(centers + grp * DD + 8 * l8);
        const float4 cb4 = *(const float4*)(centers + grp * DD + 8 * l8 + 4);
        x[0] = 0.5f * (ca.x  - mean_s[8*l8+0]);
        x[1] = 0.5f * (ca.y  - mean_s[8*l8+1]);
        x[2] = 0.5f * (ca.z  - mean_s[8*l8+2]);
        x[3] = 0.5f * (ca.w  - mean_s[8*l8+3]);
        x[4] = 0.5f * (cb4.x - mean_s[8*l8+4]);
        x[5] = 0.5f * (cb4.y - mean_s[8*l8+5]);
        x[6] = 0.5f * (cb4.z - mean_s[8*l8+6]);
        x[7] = 0.5f * (cb4.w - mean_s[8*l8+7]);
        for (int k8 = 0; k8 < 8; ++k8) {
            #pragma unroll
            for (int kk = 0; kk < 8; ++kk) {
                int k = 8 * k8 + kk;
                float zk = __shfl(x[kk], (lw & 56) | k8, 64);
                #pragma unroll
                for (int s = 0; s < 8; ++s)
                    x[s] -= LmT[k * STR + 8 * l8 + s] * zk;   // zero-filled rows
            }
        }
        #pragma unroll
        for (int s = 0; s < 8; ++s)
            H_s[grp * STR + 8 * l8 + s] = x[s] * sqrtf(invd_s[8 * l8 + s]);
    }
    __syncthreads();

    // ================= PHASE 2: M1 = Dl cov Dl + I =================
    // A1 built NOW (cov re-read; L2-resident: 4 blk/CU x 16 KB = 2 MB/XCD).
    float A1[4][4];
    {
        const float il0 = invl_s[4*rb+0], il1 = invl_s[4*rb+1],
                    il2 = invl_s[4*rb+2], il3 = invl_s[4*rb+3];
        #pragma unroll
        for (int c = 0; c < 4; ++c) {
            const int gr = 4 * cb + c;
            const float4 cv = *(const float4*)(cvb + (size_t)gr * DD + 4 * rb);
            const float ilc = invl_s[gr];
            A1[0][c] = cv.x * il0 * ilc + ((4*rb+0 == gr) ? 1.0f : 0.0f);
            A1[1][c] = cv.y * il1 * ilc + ((4*rb+1 == gr) ? 1.0f : 0.0f);
            A1[2][c] = cv.z * il2 * ilc + ((4*rb+2 == gr) ? 1.0f : 0.0f);
            A1[3][c] = cv.w * il3 * ilc + ((4*rb+3 == gr) ? 1.0f : 0.0f);
        }
    }
    // M1 panel 0 (wave 0) overlapped with Gram/Q/U (all waves)
    if (wv == 0) factor_panel(A1, 0, LmT, diag_s, invd_s, lw);
    {
        float acc[4] = {0.f, 0.f, 0.f, 0.f};
        const int rot = 2 * l8;   // per-lane column rotation: kills bank conflicts
        #pragma unroll
        for (int e = 0; e < 16; ++e) {
            const int e4 = 4 * ((e + rot) & 15);
            const float4 hn = *(const float4*)&H_s[grp * STR + e4];
            #pragma unroll
            for (int mm = 0; mm < 4; ++mm) {
                const float4 hm = *(const float4*)&H_s[(4 * l8 + mm) * STR + e4];
                float s0 = hn.x + hm.x, s1 = hn.y + hm.y;
                float s2 = hn.z + hm.z, s3 = hn.w + hm.w;
                acc[mm] += s0*s0 + s1*s1 + s2*s2 + s3*s3;   // |h_n+h_m|^2
            }
        }
        const float4 e1 = *(const float4*)&ws[grp * NN + 4 * l8];
        float Q0 = cq * expf(e1.x - 0.5f * acc[0]);
        float Q1 = cq * expf(e1.y - 0.5f * acc[1]);
        float Q2 = cq * expf(e1.z - 0.5f * acc[2]);
        float Q3 = cq * expf(e1.w - 0.5f * acc[3]);
        float u[8];
        #pragma unroll
        for (int a = 0; a < 8; ++a) {
            u[a] = Q0 * w9_s[(4*l8+0)*W9 + a] + Q1 * w9_s[(4*l8+1)*W9 + a]
                 + Q2 * w9_s[(4*l8+2)*W9 + a] + Q3 * w9_s[(4*l8+3)*W9 + a];
            u[a] += __shfl_xor(u[a], 1, 64);
            u[a] += __shfl_xor(u[a], 2, 64);
            u[a] += __shfl_xor(u[a], 4, 64);
        }
        float uv = (l8 == 0) ? u[0] : (l8 == 1) ? u[1] : (l8 == 2) ? u[2] : (l8 == 3) ? u[3]
                 : (l8 == 4) ? u[4] : (l8 == 5) ? u[5] : (l8 == 6) ? u[6] : u[7];
        U_s[grp * W9 + l8] = uv;   // U = Q w
    }
    #pragma unroll 1
    for (int p = 0; p < 3; ++p) {
        __syncthreads();
        trailing_update(A1, p, LmT, diag_s, rb, cb);
        if (wv == p + 1) factor_panel(A1, p + 1, LmT, diag_s, invd_s, lw);
    }
    __syncthreads();

    // per-wave logdet1
    float logdet1;
    {
        float v = logf(diag_s[lw]);
        #pragma unroll
        for (int o = 1; o < 64; o <<= 1) v += __shfl_xor(v, o, 64);
        logdet1 = v;
    }

    // ---- forward solve M1 (32 RHS) -> phi, phiw ----
    {
        float x[8];
        const float4 ca  = *(const float4*)(centers + grp * DD + 8 * l8);
        const float4 cb4 = *(const float4*)(centers + grp * DD + 8 * l8 + 4);
        x[0] = (ca.x  - mean_s[8*l8+0]) * invl_s[8*l8+0];
        x[1] = (ca.y  - mean_s[8*l8+1]) * invl_s[8*l8+1];
        x[2] = (ca.z  - mean_s[8*l8+2]) * invl_s[8*l8+2];
        x[3] = (ca.w  - mean_s[8*l8+3]) * invl_s[8*l8+3];
        x[4] = (cb4.x - mean_s[8*l8+4]) * invl_s[8*l8+4];
        x[5] = (cb4.y - mean_s[8*l8+5]) * invl_s[8*l8+5];
        x[6] = (cb4.z - mean_s[8*l8+6]) * invl_s[8*l8+6];
        x[7] = (cb4.w - mean_s[8*l8+7]) * invl_s[8*l8+7];
        for (int k8 = 0; k8 < 8; ++k8) {
            #pragma unroll
            for (int kk = 0; kk < 8; ++kk) {
                int k = 8 * k8 + kk;
                float zk = __shfl(x[kk], (lw & 56) | k8, 64);
                #pragma unroll
                for (int s = 0; s < 8; ++s)
                    x[s] -= LmT[k * STR + 8 * l8 + s] * zk;
            }
        }
        float qf = 0.f;
        #pragma unroll
        for (int s = 0; s < 8; ++s) qf += x[s] * x[s] * invd_s[8 * l8 + s];
        qf += __shfl_xor(qf, 1, 64);
        qf += __shfl_xor(qf, 2, 64);
        qf += __shfl_xor(qf, 4, 64);
        float ph = expf(-0.5f * (logdet1 + qf));   // normalizer * exp_term
        phiw_s[grp * W9 + l8] = ph * w9_s[grp * W9 + l8];
    }
    __syncthreads();

    // ---- K[d][a] = sum_n s_n[d] * phiw[n][a] (centers from L1/L2) ----
    {
        const int d = t >> 2, a0 = (t & 3) * 2;
        const float md = mean_s[d], il = invl_s[d];
        float k0 = 0.f, k1 = 0.f;
        for (int n = 0; n < NN; ++n) {
            float sv = (centers[n * DD + d] - md) * il;
            k0 += sv * phiw_s[n * W9 + a0];
            k1 += sv * phiw_s[n * W9 + a0 + 1];
        }
        K_s[d * W9 + a0]     = k0;
        K_s[d * W9 + a0 + 1] = k1;
    }
    __syncthreads();

    // ---- parallel: wave0 solve B1^{-1}K (8 RHS) | amean | acr = w^T U ----
    if (t < 64) {
        const int aa = t >> 3;   // RHS index
        float y[8];
        #pragma unroll
        for (int s = 0; s < 8; ++s) y[s] = K_s[(8 * l8 + s) * W9 + aa];
        for (int k8 = 0; k8 < 8; ++k8) {              // forward (unit-L)
            #pragma unroll
            for (int kk = 0; kk < 8; ++kk) {
                int k = 8 * k8 + kk;
                float zk = __shfl(y[kk], (t & 56) | k8, 64);
                #pragma unroll
                for (int s = 0; s < 8; ++s)
                    y[s] -= LmT[k * STR + 8 * l8 + s] * zk;
            }
        }
        #pragma unroll
        for (int s = 0; s < 8; ++s) y[s] *= invd_s[8 * l8 + s];
        // backward (L^T), dot-form: reads L^T ROWS (contiguous, conflict-free);
        // zero-filled entries auto-mask k<=i.
        for (int i8 = 7; i8 >= 0; --i8) {
            #pragma unroll
            for (int ii = 7; ii >= 0; --ii) {
                const int i = 8 * i8 + ii;
                const float4 r0 = *(const float4*)&LmT[i * STR + 8 * l8];
                const float4 r1 = *(const float4*)&LmT[i * STR + 8 * l8 + 4];
                float part = r0.x*y[0] + r0.y*y[1] + r0.z*y[2] + r0.w*y[3]
                           + r1.x*y[4] + r1.y*y[5] + r1.z*y[6] + r1.w*y[7];
                part += __shfl_xor(part, 1, 64);
                part += __shfl_xor(part, 2, 64);
                part += __shfl_xor(part, 4, 64);
                if (l8 == i8) y[ii] -= part;
            }
        }
        #pragma unroll
        for (int s = 0; s < 8; ++s)
            cp_s[(8 * l8 + s) * W9 + aa] = y[s] * invl_s[8 * l8 + s];
    } else if (t < 72) {
        int a = t - 64;
        float am = 0.f;
        for (int n = 0; n < NN; ++n) am += phiw_s[n * W9 + a];
        am_s[a] = am;
    } else if (t >= 128 && t < 192) {
        int t2 = t - 128, a = t2 >> 3, c = t2 & 7;
        float acc2 = 0.f;
        for (int n = 0; n < NN; ++n) acc2 += w9_s[n * W9 + a] * U_s[n * W9 + c];
        acr_s[a * W9 + c] = acc2;
    }
    __syncthreads();

    // ---- squash + outputs ----
    float* out0 = out;
    float* out1 = out + (size_t)NBATCH * AA;
    float* out2 = out + (size_t)NBATCH * AA + (size_t)NBATCH * AA * AA;
    if (t < 64) {
        const int a = t >> 3, c = t & 7;
        const float ama = am_s[a], amc = am_s[c];
        const float vac = 0.5f * (acr_s[a * W9 + c] + acr_s[c * W9 + a])
                        - ama * amc + ((a == c) ? 1e-6f : 0.0f);
        const float dca = acr_s[a * W9 + a] - ama * ama + 1e-6f;
        const float dcc = acr_s[c * W9 + c] - amc * amc + 1e-6f;
        const float q = expf(-0.5f * (dca + dcc));
        // expm1 formulation avoids catastrophic cancellation at vac ~ 1e-6
        const float sq = 0.5f * q * (expm1f(vac) * cosf(ama - amc)
                                   - expm1f(-vac) * cosf(ama + amc));
        out1[(size_t)b * 64 + t] = sq;
        if (t < AA) {
            float dct = acr_s[t * W9 + t] - am_s[t] * am_s[t] + 1e-6f;
            float e = expf(-0.5f * dct);
            out0[(size_t)b * AA + t] = e * sinf(am_s[t]);
            Ca_s[t] = e * cosf(am_s[t]);
        }
    }
    __syncthreads();
    #pragma unroll
    for (int e = 0; e < 2; ++e) {
        int idx = t + 256 * e;
        out2[(size_t)b * 512 + idx] = cp_s[(idx >> 3) * W9 + (idx & 7)] * Ca_s[idx & 7];
    }
}

extern "C" void kernel_launch(void* const* d_in, const int* in_sizes, int n_in,
                              void* d_out, int out_size, void* d_ws, size_t ws_size,
                              hipStream_t stream) {
    (void)in_sizes; (void)n_in; (void)out_size; (void)ws_size;
    const float* mean    = (const float*)d_in[0];
    const float* cov     = (const float*)d_in[1];
    const float* centers = (const float*)d_in[2];
    const float* weights = (const float*)d_in[3];
    const float* ls      = (const float*)d_in[4];
    float* ws = (float*)d_ws;
    float* o  = (float*)d_out;
    rbf_prep<<<4, 256, 0, stream>>>(centers, ls, ws);
    rbf_main<<<NBATCH, 256, 0, stream>>>(mean, cov, centers, weights, ls, ws, o);
}

// Round 4
// 281.058 us; speedup vs baseline: 1.9783x; 1.7372x over previous
//
#include <hip/hip_runtime.h>
#include <math.h>

// RBFController: B=2048, N=32 centers, D=64 dims, A=8 actions.
// One 256-thread block per batch element. Two SPD 64x64 LDL^T factorizations
// done SEQUENTIALLY (A2 then A1; A1 tile built late from an L2-resident cov
// re-read so only ONE 4x4 register tile is live at a time). Wave-local
// blocked-panel factorization (shfl-only panels, 4 barriers/matrix),
// wave-synchronous triangular solves.
//
// VGPR/occupancy model (measured R1-R3): waves/SIMD = floor(256 / VGPR_Count).
//   R2: (256,4) -> cap 64 -> massive spills (900 MB scratch traffic).
//   R3: unconstrained -> 164 VGPR -> 1 wave/SIMD (11.9% occ), latency-starved.
//   Now: (256,3) -> cap 85; R1 fit BOTH tiles in 88, so one-tile code fits.

#define DD 64
#define NN 32
#define AA 8
#define NBATCH 2048
#define STR 68   // L^T / H row stride (words): 272 B, 16B-aligned rows
#define W9 9     // padded stride for N x A / D x A arrays (kills 8/16-way conflicts)

// ---------------- prep: exp1[n][m] table + logdet_lh scalar ----------------
__global__ void rbf_prep(const float* __restrict__ centers,
                         const float* __restrict__ ls,
                         float* __restrict__ ws) {
    __shared__ float cen_s[NN * DD];
    __shared__ float il2_s[DD];
    int t = threadIdx.x;
    for (int e = t; e < NN * DD; e += 256) cen_s[e] = centers[e];
    if (t < DD) { float l = ls[t]; il2_s[t] = 1.0f / (l * l); }
    __syncthreads();
    int p = blockIdx.x * 256 + t;
    if (p < NN * NN) {
        int n = p >> 5, m = p & 31;
        float acc = 0.f;
        for (int d = 0; d < DD; ++d) {
            float df = cen_s[n * DD + d] - cen_s[m * DD + d];
            acc += df * df * il2_s[d];
        }
        ws[p] = -0.25f * acc;              // exp1[n][m]
    }
    if (blockIdx.x == 0 && t < DD) {
        float l = ls[t];
        float v = logf(0.5f * l * l);
        #pragma unroll
        for (int o = 1; o < 64; o <<= 1) v += __shfl_xor(v, o, 64);
        if (t == 0) ws[NN * NN] = v;       // logdet_lh
    }
}

// Wave-local panel factorization: wave owns cols 16p..16p+15 of A in its
// register tiles (lane lw: rows 4*(lw&15).., cols 16p+4*(lw>>4)..). Pure
// shfl pivot-column exchange; writes zero-filled L^T rows to LDS.
__device__ __forceinline__ void factor_panel(float (&A)[4][4], const int p,
    float* __restrict__ LmT, float* __restrict__ diag_s, float* __restrict__ invd_s,
    const int lw)
{
    const int rb  = lw & 15;
    const int cbl = lw >> 4;               // 0..3 (panel-local col tile)
    const int c0  = 16 * p + 4 * cbl;
    const int r0  = 4 * rb;
    #pragma unroll
    for (int jj = 0; jj < 16; ++jj) {
        const int q  = jj >> 2;
        const int ci = jj & 3;
        const int j  = 16 * p + jj;
        const int fsrc = rb | (q << 4);               // same row-tile, owner col-tile
        const int hsrc = (4 * p + cbl) | (q << 4);    // row-tile = my col range
        const int dsrc = (4 * p + q) | (q << 4);      // pivot element owner
        float d  = __shfl(A[ci][ci], dsrc, 64);
        float f0 = __shfl(A[0][ci], fsrc, 64);
        float f1 = __shfl(A[1][ci], fsrc, 64);
        float f2 = __shfl(A[2][ci], fsrc, 64);
        float f3 = __shfl(A[3][ci], fsrc, 64);
        float h0 = __shfl(A[0][ci], hsrc, 64);
        float h1 = __shfl(A[1][ci], hsrc, 64);
        float h2 = __shfl(A[2][ci], hsrc, 64);
        float h3 = __shfl(A[3][ci], hsrc, 64);
        float id = __builtin_amdgcn_rcpf(d);   // cond(A) ~ 1; ~1ulp fine
        float fr[4];
        fr[0] = (r0 + 0 > j) ? f0 : 0.f;
        fr[1] = (r0 + 1 > j) ? f1 : 0.f;
        fr[2] = (r0 + 2 > j) ? f2 : 0.f;
        fr[3] = (r0 + 3 > j) ? f3 : 0.f;
        float hc[4];
        hc[0] = (c0 + 0 > j) ? h0 * id : 0.f;
        hc[1] = (c0 + 1 > j) ? h1 * id : 0.f;
        hc[2] = (c0 + 2 > j) ? h2 * id : 0.f;
        hc[3] = (c0 + 3 > j) ? h3 * id : 0.f;
        #pragma unroll
        for (int s = 0; s < 4; ++s)
            #pragma unroll
            for (int c = 0; c < 4; ++c)
                A[s][c] -= fr[s] * hc[c];
        if (cbl == 0) {   // 16 lanes write full zero-filled L^T row j
            float4 v = make_float4(fr[0] * id, fr[1] * id, fr[2] * id, fr[3] * id);
            *(float4*)&LmT[j * STR + r0] = v;
        }
        if (lw == jj) { diag_s[j] = d; invd_s[j] = id; }
    }
}

// Rank-16 trailing update from panel p. Zero-filled L^T rows auto-mask
// rows<=k and cols<=k — unpredicated.
__device__ __forceinline__ void trailing_update(float (&A)[4][4], const int p,
    const float* __restrict__ LmT, const float* __restrict__ diag_s,
    const int rb, const int cb)
{
    #pragma unroll
    for (int kk = 0; kk < 16; ++kk) {
        const int k = 16 * p + kk;
        const float4 Lr = *(const float4*)&LmT[k * STR + 4 * rb];
        const float4 Lc = *(const float4*)&LmT[k * STR + 4 * cb];
        const float dk = diag_s[k];
        const float hc0 = Lc.x * dk, hc1 = Lc.y * dk, hc2 = Lc.z * dk, hc3 = Lc.w * dk;
        A[0][0] -= Lr.x * hc0; A[0][1] -= Lr.x * hc1; A[0][2] -= Lr.x * hc2; A[0][3] -= Lr.x * hc3;
        A[1][0] -= Lr.y * hc0; A[1][1] -= Lr.y * hc1; A[1][2] -= Lr.y * hc2; A[1][3] -= Lr.y * hc3;
        A[2][0] -= Lr.z * hc0; A[2][1] -= Lr.z * hc1; A[2][2] -= Lr.z * hc2; A[2][3] -= Lr.z * hc3;
        A[3][0] -= Lr.w * hc0; A[3][1] -= Lr.w * hc1; A[3][2] -= Lr.w * hc2; A[3][3] -= Lr.w * hc3;
    }
}

__global__ __launch_bounds__(256, 3) void rbf_main(
    const float* __restrict__ mean,      // (B,64)
    const float* __restrict__ cov,       // (B,64,64)
    const float* __restrict__ centers,   // (32,64)
    const float* __restrict__ weights,   // (32,8)
    const float* __restrict__ ls,        // (64,)
    const float* __restrict__ ws,        // exp1[1024], logdet_lh at [1024]
    float* __restrict__ out)
{
    __shared__ __align__(16) float LmT[DD * STR];   // 17408 B (L2^T then L1^T)
    __shared__ __align__(16) float H_s[NN * STR];   // 8704 B
    __shared__ __align__(16) float K_s[DD * W9];    // 2304 B
    __shared__ __align__(16) float cp_s[DD * W9];   // 2304 B
    __shared__ float diag_s[DD], invd_s[DD];
    __shared__ float mean_s[DD], invl_s[DD], l2h_s[DD];
    __shared__ float w9_s[NN * W9], phiw_s[NN * W9], U_s[NN * W9];
    __shared__ float am_s[AA], acr_s[AA * W9], Ca_s[AA];
    __shared__ float ldlh_s;

    const int t   = threadIdx.x;
    const int b   = blockIdx.x;
    const int lw  = t & 63;
    const int wv  = t >> 6;
    const int rb  = t & 15;   // row tile (rows 4rb..4rb+3)
    const int cb  = t >> 4;   // col tile (cols 4cb..4cb+3); wave w owns cols 16w..16w+15
    const int grp = t >> 3;   // RHS group 0..31 in solves
    const int l8  = t & 7;    // lane-in-group (rows 8*l8..8*l8+7)
    const float* cvb = cov + (size_t)b * DD * DD;

    // ---- stage small arrays ----
    if (t < DD) {
        float l = ls[t];
        invl_s[t] = 1.0f / l;
        l2h_s[t]  = 0.5f * l * l;
        mean_s[t] = mean[(size_t)b * DD + t];
    }
    w9_s[(t >> 3) * W9 + (t & 7)] = weights[t];
    if (t == 0) ldlh_s = ws[NN * NN];
    __syncthreads();

    // ================= PHASE 1: M2 = cov + diag(l^2/2) =================
    {
        float A2[4][4];
        #pragma unroll
        for (int c = 0; c < 4; ++c) {
            const int gr = 4 * cb + c;   // symmetric load: read rows 4cb.. (coalesced)
            const float4 cv = *(const float4*)(cvb + (size_t)gr * DD + 4 * rb);
            A2[0][c] = cv.x + ((4*rb+0 == gr) ? l2h_s[gr] : 0.0f);
            A2[1][c] = cv.y + ((4*rb+1 == gr) ? l2h_s[gr] : 0.0f);
            A2[2][c] = cv.z + ((4*rb+2 == gr) ? l2h_s[gr] : 0.0f);
            A2[3][c] = cv.w + ((4*rb+3 == gr) ? l2h_s[gr] : 0.0f);
        }
        if (wv == 0) factor_panel(A2, 0, LmT, diag_s, invd_s, lw);
        #pragma unroll 1
        for (int p = 0; p < 3; ++p) {
            __syncthreads();
            trailing_update(A2, p, LmT, diag_s, rb, cb);
            if (wv == p + 1) factor_panel(A2, p + 1, LmT, diag_s, invd_s, lw);
        }
        __syncthreads();
    }

    // per-wave (redundant) logdet2 -> cq; avoids extra barrier
    float cq;
    {
        float v = logf(diag_s[lw]);
        #pragma unroll
        for (int o = 1; o < 64; o <<= 1) v += __shfl_xor(v, o, 64);
        cq = expf(0.5f * (ldlh_s - v));
    }

    // ---- forward solve M2 (32 RHS): H = D^{-1/2} L2^{-1} (c_n - mean)/2 ----
    {
        float x[8];
        const float4 ca  = *(const float4*)(centers + grp * DD + 8 * l8);
        const float4 cb4 = *(const float4*)(centers + grp * DD + 8 * l8 + 4);
        x[0] = 0.5f * (ca.x  - mean_s[8*l8+0]);
        x[1] = 0.5f * (ca.y  - mean_s[8*l8+1]);
        x[2] = 0.5f * (ca.z  - mean_s[8*l8+2]);
        x[3] = 0.5f * (ca.w  - mean_s[8*l8+3]);
        x[4] = 0.5f * (cb4.x - mean_s[8*l8+4]);
        x[5] = 0.5f * (cb4.y - mean_s[8*l8+5]);
        x[6] = 0.5f * (cb4.z - mean_s[8*l8+6]);
        x[7] = 0.5f * (cb4.w - mean_s[8*l8+7]);
        for (int k8 = 0; k8 < 8; ++k8) {
            #pragma unroll
            for (int kk = 0; kk < 8; ++kk) {
                int k = 8 * k8 + kk;
                float zk = __shfl(x[kk], (lw & 56) | k8, 64);
                #pragma unroll
                for (int s = 0; s < 8; ++s)
                    x[s] -= LmT[k * STR + 8 * l8 + s] * zk;   // zero-filled rows
            }
        }
        #pragma unroll
        for (int s = 0; s < 8; ++s)
            H_s[grp * STR + 8 * l8 + s] = x[s] * sqrtf(invd_s[8 * l8 + s]);
    }
    __syncthreads();

    // ================= PHASE 2: M1 = Dl cov Dl + I =================
    // A1 built NOW (cov re-read; L2-resident: ~3 blk/CU x 16 KB working set).
    float A1[4][4];
    {
        const float il0 = invl_s[4*rb+0], il1 = invl_s[4*rb+1],
                    il2 = invl_s[4*rb+2], il3 = invl_s[4*rb+3];
        #pragma unroll
        for (int c = 0; c < 4; ++c) {
            const int gr = 4 * cb + c;
            const float4 cv = *(const float4*)(cvb + (size_t)gr * DD + 4 * rb);
            const float ilc = invl_s[gr];
            A1[0][c] = cv.x * il0 * ilc + ((4*rb+0 == gr) ? 1.0f : 0.0f);
            A1[1][c] = cv.y * il1 * ilc + ((4*rb+1 == gr) ? 1.0f : 0.0f);
            A1[2][c] = cv.z * il2 * ilc + ((4*rb+2 == gr) ? 1.0f : 0.0f);
            A1[3][c] = cv.w * il3 * ilc + ((4*rb+3 == gr) ? 1.0f : 0.0f);
        }
    }
    // M1 panel 0 (wave 0) overlapped with Gram/Q/U (all waves)
    if (wv == 0) factor_panel(A1, 0, LmT, diag_s, invd_s, lw);
    {
        float acc[4] = {0.f, 0.f, 0.f, 0.f};
        const int rot = 2 * l8;   // per-lane column rotation: kills bank conflicts
        #pragma unroll
        for (int e = 0; e < 16; ++e) {
            const int e4 = 4 * ((e + rot) & 15);
            const float4 hn = *(const float4*)&H_s[grp * STR + e4];
            #pragma unroll
            for (int mm = 0; mm < 4; ++mm) {
                const float4 hm = *(const float4*)&H_s[(4 * l8 + mm) * STR + e4];
                float s0 = hn.x + hm.x, s1 = hn.y + hm.y;
                float s2 = hn.z + hm.z, s3 = hn.w + hm.w;
                acc[mm] += s0*s0 + s1*s1 + s2*s2 + s3*s3;   // |h_n+h_m|^2
            }
        }
        const float4 e1 = *(const float4*)&ws[grp * NN + 4 * l8];
        float Q0 = cq * expf(e1.x - 0.5f * acc[0]);
        float Q1 = cq * expf(e1.y - 0.5f * acc[1]);
        float Q2 = cq * expf(e1.z - 0.5f * acc[2]);
        float Q3 = cq * expf(e1.w - 0.5f * acc[3]);
        float u[8];
        #pragma unroll
        for (int a = 0; a < 8; ++a) {
            u[a] = Q0 * w9_s[(4*l8+0)*W9 + a] + Q1 * w9_s[(4*l8+1)*W9 + a]
                 + Q2 * w9_s[(4*l8+2)*W9 + a] + Q3 * w9_s[(4*l8+3)*W9 + a];
            u[a] += __shfl_xor(u[a], 1, 64);
            u[a] += __shfl_xor(u[a], 2, 64);
            u[a] += __shfl_xor(u[a], 4, 64);
        }
        float uv = (l8 == 0) ? u[0] : (l8 == 1) ? u[1] : (l8 == 2) ? u[2] : (l8 == 3) ? u[3]
                 : (l8 == 4) ? u[4] : (l8 == 5) ? u[5] : (l8 == 6) ? u[6] : u[7];
        U_s[grp * W9 + l8] = uv;   // U = Q w
    }
    #pragma unroll 1
    for (int p = 0; p < 3; ++p) {
        __syncthreads();
        trailing_update(A1, p, LmT, diag_s, rb, cb);
        if (wv == p + 1) factor_panel(A1, p + 1, LmT, diag_s, invd_s, lw);
    }
    __syncthreads();

    // per-wave logdet1
    float logdet1;
    {
        float v = logf(diag_s[lw]);
        #pragma unroll
        for (int o = 1; o < 64; o <<= 1) v += __shfl_xor(v, o, 64);
        logdet1 = v;
    }

    // ---- forward solve M1 (32 RHS) -> phi, phiw ----
    {
        float x[8];
        const float4 ca  = *(const float4*)(centers + grp * DD + 8 * l8);
        const float4 cb4 = *(const float4*)(centers + grp * DD + 8 * l8 + 4);
        x[0] = (ca.x  - mean_s[8*l8+0]) * invl_s[8*l8+0];
        x[1] = (ca.y  - mean_s[8*l8+1]) * invl_s[8*l8+1];
        x[2] = (ca.z  - mean_s[8*l8+2]) * invl_s[8*l8+2];
        x[3] = (ca.w  - mean_s[8*l8+3]) * invl_s[8*l8+3];
        x[4] = (cb4.x - mean_s[8*l8+4]) * invl_s[8*l8+4];
        x[5] = (cb4.y - mean_s[8*l8+5]) * invl_s[8*l8+5];
        x[6] = (cb4.z - mean_s[8*l8+6]) * invl_s[8*l8+6];
        x[7] = (cb4.w - mean_s[8*l8+7]) * invl_s[8*l8+7];
        for (int k8 = 0; k8 < 8; ++k8) {
            #pragma unroll
            for (int kk = 0; kk < 8; ++kk) {
                int k = 8 * k8 + kk;
                float zk = __shfl(x[kk], (lw & 56) | k8, 64);
                #pragma unroll
                for (int s = 0; s < 8; ++s)
                    x[s] -= LmT[k * STR + 8 * l8 + s] * zk;
            }
        }
        float qf = 0.f;
        #pragma unroll
        for (int s = 0; s < 8; ++s) qf += x[s] * x[s] * invd_s[8 * l8 + s];
        qf += __shfl_xor(qf, 1, 64);
        qf += __shfl_xor(qf, 2, 64);
        qf += __shfl_xor(qf, 4, 64);
        float ph = expf(-0.5f * (logdet1 + qf));   // normalizer * exp_term
        phiw_s[grp * W9 + l8] = ph * w9_s[grp * W9 + l8];
    }
    __syncthreads();

    // ---- K[d][a] = sum_n s_n[d] * phiw[n][a] (centers from L1/L2) ----
    {
        const int d = t >> 2, a0 = (t & 3) * 2;
        const float md = mean_s[d], il = invl_s[d];
        float k0 = 0.f, k1 = 0.f;
        for (int n = 0; n < NN; ++n) {
            float sv = (centers[n * DD + d] - md) * il;
            k0 += sv * phiw_s[n * W9 + a0];
            k1 += sv * phiw_s[n * W9 + a0 + 1];
        }
        K_s[d * W9 + a0]     = k0;
        K_s[d * W9 + a0 + 1] = k1;
    }
    __syncthreads();

    // ---- parallel: wave0 solve B1^{-1}K (8 RHS) | amean | acr = w^T U ----
    if (t < 64) {
        const int aa = t >> 3;   // RHS index
        float y[8];
        #pragma unroll
        for (int s = 0; s < 8; ++s) y[s] = K_s[(8 * l8 + s) * W9 + aa];
        for (int k8 = 0; k8 < 8; ++k8) {              // forward (unit-L)
            #pragma unroll
            for (int kk = 0; kk < 8; ++kk) {
                int k = 8 * k8 + kk;
                float zk = __shfl(y[kk], (t & 56) | k8, 64);
                #pragma unroll
                for (int s = 0; s < 8; ++s)
                    y[s] -= LmT[k * STR + 8 * l8 + s] * zk;
            }
        }
        #pragma unroll
        for (int s = 0; s < 8; ++s) y[s] *= invd_s[8 * l8 + s];
        // backward (L^T), dot-form: reads L^T ROWS (contiguous, conflict-free);
        // zero-filled entries auto-mask k<=i.
        for (int i8 = 7; i8 >= 0; --i8) {
            #pragma unroll
            for (int ii = 7; ii >= 0; --ii) {
                const int i = 8 * i8 + ii;
                const float4 r0 = *(const float4*)&LmT[i * STR + 8 * l8];
                const float4 r1 = *(const float4*)&LmT[i * STR + 8 * l8 + 4];
                float part = r0.x*y[0] + r0.y*y[1] + r0.z*y[2] + r0.w*y[3]
                           + r1.x*y[4] + r1.y*y[5] + r1.z*y[6] + r1.w*y[7];
                part += __shfl_xor(part, 1, 64);
                part += __shfl_xor(part, 2, 64);
                part += __shfl_xor(part, 4, 64);
                if (l8 == i8) y[ii] -= part;
            }
        }
        #pragma unroll
        for (int s = 0; s < 8; ++s)
            cp_s[(8 * l8 + s) * W9 + aa] = y[s] * invl_s[8 * l8 + s];
    } else if (t < 72) {
        int a = t - 64;
        float am = 0.f;
        for (int n = 0; n < NN; ++n) am += phiw_s[n * W9 + a];
        am_s[a] = am;
    } else if (t >= 128 && t < 192) {
        int t2 = t - 128, a = t2 >> 3, c = t2 & 7;
        float acc2 = 0.f;
        for (int n = 0; n < NN; ++n) acc2 += w9_s[n * W9 + a] * U_s[n * W9 + c];
        acr_s[a * W9 + c] = acc2;
    }
    __syncthreads();

    // ---- squash + outputs ----
    float* out0 = out;
    float* out1 = out + (size_t)NBATCH * AA;
    float* out2 = out + (size_t)NBATCH * AA + (size_t)NBATCH * AA * AA;
    if (t < 64) {
        const int a = t >> 3, c = t & 7;
        const float ama = am_s[a], amc = am_s[c];
        const float vac = 0.5f * (acr_s[a * W9 + c] + acr_s[c * W9 + a])
                        - ama * amc + ((a == c) ? 1e-6f : 0.0f);
        const float dca = acr_s[a * W9 + a] - ama * ama + 1e-6f;
        const float dcc = acr_s[c * W9 + c] - amc * amc + 1e-6f;
        const float q = expf(-0.5f * (dca + dcc));
        // expm1 formulation avoids catastrophic cancellation at vac ~ 1e-6
        const float sq = 0.5f * q * (expm1f(vac) * cosf(ama - amc)
                                   - expm1f(-vac) * cosf(ama + amc));
        out1[(size_t)b * 64 + t] = sq;
        if (t < AA) {
            float dct = acr_s[t * W9 + t] - am_s[t] * am_s[t] + 1e-6f;
            float e = expf(-0.5f * dct);
            out0[(size_t)b * AA + t] = e * sinf(am_s[t]);
            Ca_s[t] = e * cosf(am_s[t]);
        }
    }
    __syncthreads();
    #pragma unroll
    for (int e = 0; e < 2; ++e) {
        int idx = t + 256 * e;
        out2[(size_t)b * 512 + idx] = cp_s[(idx >> 3) * W9 + (idx & 7)] * Ca_s[idx & 7];
    }
}

extern "C" void kernel_launch(void* const* d_in, const int* in_sizes, int n_in,
                              void* d_out, int out_size, void* d_ws, size_t ws_size,
                              hipStream_t stream) {
    (void)in_sizes; (void)n_in; (void)out_size; (void)ws_size;
    const float* mean    = (const float*)d_in[0];
    const float* cov     = (const float*)d_in[1];
    const float* centers = (const float*)d_in[2];
    const float* weights = (const float*)d_in[3];
    const float* ls      = (const float*)d_in[4];
    float* ws = (float*)d_ws;
    float* o  = (float*)d_out;
    rbf_prep<<<4, 256, 0, stream>>>(centers, ls, ws);
    rbf_main<<<NBATCH, 256, 0, stream>>>(mean, cov, centers, weights, ls, ws, o);
}

// Round 6
// 231.182 us; speedup vs baseline: 2.4051x; 1.2157x over previous
//
#include <hip/hip_runtime.h>
#include <math.h>

// RBFController: B=2048, N=32 centers, D=64 dims, A=8 actions.
// One 256-thread block per batch element. Two SPD 64x64 LDL^T factorizations
// FUSED with SHIFTED OWNERSHIP: wave w owns M2 cols 16w.. and M1 cols
// 16*((w+2)&3).. , so in each panel slot TWO DIFFERENT waves factor panel p
// of the two matrices in parallel (both legally own those columns).
// R4's NaN bug: a wave factored a panel whose columns it did NOT own.
// Forward solves for both systems fused in one k-loop.
//
// VGPR/occupancy model (measured R1-R4): waves/SIMD = floor(256/VGPR_Count).
//   (256,4)->cap64: huge spills. uncapped: 164 VGPR -> 1 wave/SIMD.
//   (256,3)->cap85: 3 waves/SIMD, mild spills (watch WRITE_SIZE).

#define DD 64
#define NN 32
#define AA 8
#define NBATCH 2048
#define STR 68   // L^T / H row stride (words): 272 B, 16B-aligned rows
#define W9 9     // padded stride for N x A arrays (kills 8/16-way conflicts)

// ---------------- prep: exp1[n][m] table + logdet_lh scalar ----------------
__global__ void rbf_prep(const float* __restrict__ centers,
                         const float* __restrict__ ls,
                         float* __restrict__ ws) {
    __shared__ float cen_s[NN * DD];
    __shared__ float il2_s[DD];
    int t = threadIdx.x;
    for (int e = t; e < NN * DD; e += 256) cen_s[e] = centers[e];
    if (t < DD) { float l = ls[t]; il2_s[t] = 1.0f / (l * l); }
    __syncthreads();
    int p = blockIdx.x * 256 + t;
    if (p < NN * NN) {
        int n = p >> 5, m = p & 31;
        float acc = 0.f;
        for (int d = 0; d < DD; ++d) {
            float df = cen_s[n * DD + d] - cen_s[m * DD + d];
            acc += df * df * il2_s[d];
        }
        ws[p] = -0.25f * acc;              // exp1[n][m]
    }
    if (blockIdx.x == 0 && t < DD) {
        float l = ls[t];
        float v = logf(0.5f * l * l);
        #pragma unroll
        for (int o = 1; o < 64; o <<= 1) v += __shfl_xor(v, o, 64);
        if (t == 0) ws[NN * NN] = v;       // logdet_lh
    }
}

// Wave-local panel factorization. PRECONDITION: the executing wave owns
// cols 16p..16p+15 of A in its register tiles (lane lw: rows 4*(lw&15)..,
// panel-local col tile lw>>4). Pure shfl pivot exchange; writes zero-filled
// L^T rows to LDS. Ownership-shift invariant (panel-local indexing).
__device__ __forceinline__ void factor_panel(float (&A)[4][4], const int p,
    float* __restrict__ LmT, float* __restrict__ diag_s, float* __restrict__ invd_s,
    const int lw)
{
    const int rb  = lw & 15;
    const int cbl = lw >> 4;
    const int c0  = 16 * p + 4 * cbl;
    const int r0  = 4 * rb;
    #pragma unroll
    for (int jj = 0; jj < 16; ++jj) {
        const int q  = jj >> 2;
        const int ci = jj & 3;
        const int j  = 16 * p + jj;
        const int fsrc = rb | (q << 4);
        const int hsrc = (4 * p + cbl) | (q << 4);
        const int dsrc = (4 * p + q) | (q << 4);
        float d  = __shfl(A[ci][ci], dsrc, 64);
        float f0 = __shfl(A[0][ci], fsrc, 64);
        float f1 = __shfl(A[1][ci], fsrc, 64);
        float f2 = __shfl(A[2][ci], fsrc, 64);
        float f3 = __shfl(A[3][ci], fsrc, 64);
        float h0 = __shfl(A[0][ci], hsrc, 64);
        float h1 = __shfl(A[1][ci], hsrc, 64);
        float h2 = __shfl(A[2][ci], hsrc, 64);
        float h3 = __shfl(A[3][ci], hsrc, 64);
        float id = __builtin_amdgcn_rcpf(d);   // cond(A) ~ 1; ~1ulp fine
        float fr[4];
        fr[0] = (r0 + 0 > j) ? f0 : 0.f;
        fr[1] = (r0 + 1 > j) ? f1 : 0.f;
        fr[2] = (r0 + 2 > j) ? f2 : 0.f;
        fr[3] = (r0 + 3 > j) ? f3 : 0.f;
        float hc[4];
        hc[0] = (c0 + 0 > j) ? h0 * id : 0.f;
        hc[1] = (c0 + 1 > j) ? h1 * id : 0.f;
        hc[2] = (c0 + 2 > j) ? h2 * id : 0.f;
        hc[3] = (c0 + 3 > j) ? h3 * id : 0.f;
        #pragma unroll
        for (int s = 0; s < 4; ++s)
            #pragma unroll
            for (int c = 0; c < 4; ++c)
                A[s][c] -= fr[s] * hc[c];
        if (cbl == 0) {
            float4 v = make_float4(fr[0] * id, fr[1] * id, fr[2] * id, fr[3] * id);
            *(float4*)&LmT[j * STR + r0] = v;
        }
        if (lw == jj) { diag_s[j] = d; invd_s[j] = id; }
    }
}

// Rank-16 trailing update for BOTH matrices. A2 cols at 4*cb, A1 cols at
// 4*cb1 (shifted ownership). Zero-filled L^T rows auto-mask <=k.
__device__ __forceinline__ void trailing_update2(
    float (&A1)[4][4], float (&A2)[4][4], const int p,
    const float* __restrict__ LmT1, const float* __restrict__ LmT2,
    const float* __restrict__ diag1, const float* __restrict__ diag2,
    const int rb, const int cb, const int cb1)
{
    #pragma unroll 2
    for (int kk = 0; kk < 16; ++kk) {
        const int k = 16 * p + kk;
        const float4 Lr1 = *(const float4*)&LmT1[k * STR + 4 * rb];
        const float4 Lc1 = *(const float4*)&LmT1[k * STR + 4 * cb1];
        const float4 Lr2 = *(const float4*)&LmT2[k * STR + 4 * rb];
        const float4 Lc2 = *(const float4*)&LmT2[k * STR + 4 * cb];
        const float d1 = diag1[k], d2 = diag2[k];
        {
            const float h0 = Lc1.x * d1, h1 = Lc1.y * d1, h2 = Lc1.z * d1, h3 = Lc1.w * d1;
            A1[0][0] -= Lr1.x * h0; A1[0][1] -= Lr1.x * h1; A1[0][2] -= Lr1.x * h2; A1[0][3] -= Lr1.x * h3;
            A1[1][0] -= Lr1.y * h0; A1[1][1] -= Lr1.y * h1; A1[1][2] -= Lr1.y * h2; A1[1][3] -= Lr1.y * h3;
            A1[2][0] -= Lr1.z * h0; A1[2][1] -= Lr1.z * h1; A1[2][2] -= Lr1.z * h2; A1[2][3] -= Lr1.z * h3;
            A1[3][0] -= Lr1.w * h0; A1[3][1] -= Lr1.w * h1; A1[3][2] -= Lr1.w * h2; A1[3][3] -= Lr1.w * h3;
        }
        {
            const float h0 = Lc2.x * d2, h1 = Lc2.y * d2, h2 = Lc2.z * d2, h3 = Lc2.w * d2;
            A2[0][0] -= Lr2.x * h0; A2[0][1] -= Lr2.x * h1; A2[0][2] -= Lr2.x * h2; A2[0][3] -= Lr2.x * h3;
            A2[1][0] -= Lr2.y * h0; A2[1][1] -= Lr2.y * h1; A2[1][2] -= Lr2.y * h2; A2[1][3] -= Lr2.y * h3;
            A2[2][0] -= Lr2.z * h0; A2[2][1] -= Lr2.z * h1; A2[2][2] -= Lr2.z * h2; A2[2][3] -= Lr2.z * h3;
            A2[3][0] -= Lr2.w * h0; A2[3][1] -= Lr2.w * h1; A2[3][2] -= Lr2.w * h2; A2[3][3] -= Lr2.w * h3;
        }
    }
}

__global__ __launch_bounds__(256, 3) void rbf_main(
    const float* __restrict__ mean,      // (B,64)
    const float* __restrict__ cov,       // (B,64,64)
    const float* __restrict__ centers,   // (32,64)
    const float* __restrict__ weights,   // (32,8)
    const float* __restrict__ ls,        // (64,)
    const float* __restrict__ ws,        // exp1[1024], logdet_lh at [1024]
    float* __restrict__ out)
{
    __shared__ __align__(16) float LmT1[DD * STR];  // 17408 B  L1^T (M1)
    __shared__ __align__(16) float LmT2[DD * STR];  // 17408 B  L2^T (M2)
    __shared__ __align__(16) float H_s[NN * STR];   // 8704 B
    __shared__ __align__(16) float K_s[DD * W9];    // 2304 B
    __shared__ __align__(16) float cp_s[DD * W9];   // 2304 B
    __shared__ float diag1[DD], invd1[DD], diag2[DD], invd2[DD];
    __shared__ float mean_s[DD], invl_s[DD], l2h_s[DD];
    __shared__ float w9_s[NN * W9], phiw_s[NN * W9], U_s[NN * W9];
    __shared__ float am_s[AA], acr_s[AA * W9], Ca_s[AA];
    __shared__ float ldlh_s;
    // total ~53.7 KB -> 3 blocks/CU (3*54 KB < 160 KiB)

    const int t   = threadIdx.x;
    const int b   = blockIdx.x;
    const int lw  = t & 63;
    const int wv  = t >> 6;
    const int rb  = t & 15;            // row tile (rows 4rb..4rb+3), both matrices
    const int cb  = t >> 4;            // M2 col tile; wave w owns M2 cols 16w..16w+15
    const int cb1 = (cb + 8) & 15;     // M1 col tile; wave w owns M1 cols 16*((w+2)&3)..
    const int grp = t >> 3;            // RHS group 0..31 in solves
    const int l8  = t & 7;             // lane-in-group (rows 8*l8..8*l8+7)
    const float* cvb = cov + (size_t)b * DD * DD;

    // ---- stage small arrays ----
    if (t < DD) {
        float l = ls[t];
        invl_s[t] = 1.0f / l;
        l2h_s[t]  = 0.5f * l * l;
        mean_s[t] = mean[(size_t)b * DD + t];
    }
    w9_s[(t >> 3) * W9 + (t & 7)] = weights[t];
    if (t == 0) ldlh_s = ws[NN * NN];
    __syncthreads();

    // ---- build tiles: A2 at (4rb, 4cb), A1 at (4rb, 4cb1) — symmetric loads
    float A1[4][4], A2[4][4];
    {
        #pragma unroll
        for (int c = 0; c < 4; ++c) {
            const int gr = 4 * cb + c;   // read row gr, cols 4rb.. (coalesced)
            const float4 cv = *(const float4*)(cvb + (size_t)gr * DD + 4 * rb);
            A2[0][c] = cv.x + ((4*rb+0 == gr) ? l2h_s[gr] : 0.0f);
            A2[1][c] = cv.y + ((4*rb+1 == gr) ? l2h_s[gr] : 0.0f);
            A2[2][c] = cv.z + ((4*rb+2 == gr) ? l2h_s[gr] : 0.0f);
            A2[3][c] = cv.w + ((4*rb+3 == gr) ? l2h_s[gr] : 0.0f);
        }
        const float il0 = invl_s[4*rb+0], il1 = invl_s[4*rb+1],
                    il2 = invl_s[4*rb+2], il3 = invl_s[4*rb+3];
        #pragma unroll
        for (int c = 0; c < 4; ++c) {
            const int gr = 4 * cb1 + c;  // shifted cols for M1
            const float4 cv = *(const float4*)(cvb + (size_t)gr * DD + 4 * rb);
            const float ilc = invl_s[gr];
            A1[0][c] = cv.x * il0 * ilc + ((4*rb+0 == gr) ? 1.0f : 0.0f);
            A1[1][c] = cv.y * il1 * ilc + ((4*rb+1 == gr) ? 1.0f : 0.0f);
            A1[2][c] = cv.z * il2 * ilc + ((4*rb+2 == gr) ? 1.0f : 0.0f);
            A1[3][c] = cv.w * il3 * ilc + ((4*rb+3 == gr) ? 1.0f : 0.0f);
        }
    }

    // ---- FUSED factorization: slot p -> wave p factors M2 panel p,
    //      wave (p+2)&3 factors M1 panel p (it owns those M1 columns).
    if (wv == 0) factor_panel(A2, 0, LmT2, diag2, invd2, lw);
    if (wv == 2) factor_panel(A1, 0, LmT1, diag1, invd1, lw);
    #pragma unroll 1
    for (int p = 0; p < 3; ++p) {
        __syncthreads();
        trailing_update2(A1, A2, p, LmT1, LmT2, diag1, diag2, rb, cb, cb1);
        if (wv == p + 1)         factor_panel(A2, p + 1, LmT2, diag2, invd2, lw);
        if (wv == ((p + 3) & 3)) factor_panel(A1, p + 1, LmT1, diag1, invd1, lw);
    }
    __syncthreads();

    // ---- per-wave logdets (redundant across waves; no barrier needed) ----
    float logdet1, cq;
    {
        float v1 = logf(diag1[lw]);
        float v2 = logf(diag2[lw]);
        #pragma unroll
        for (int o = 1; o < 64; o <<= 1) {
            v1 += __shfl_xor(v1, o, 64);
            v2 += __shfl_xor(v2, o, 64);
        }
        logdet1 = v1;
        cq = expf(0.5f * (ldlh_s - v2));
    }

    // ---- FUSED forward solves (32 RHS each): x1 -> phi, x2 -> H ----
    {
        float x1[8], x2[8];
        const float4 ca  = *(const float4*)(centers + grp * DD + 8 * l8);
        const float4 cb4 = *(const float4*)(centers + grp * DD + 8 * l8 + 4);
        {
            float d0 = ca.x  - mean_s[8*l8+0], d1 = ca.y  - mean_s[8*l8+1];
            float d2 = ca.z  - mean_s[8*l8+2], d3 = ca.w  - mean_s[8*l8+3];
            float d4 = cb4.x - mean_s[8*l8+4], d5 = cb4.y - mean_s[8*l8+5];
            float d6 = cb4.z - mean_s[8*l8+6], d7 = cb4.w - mean_s[8*l8+7];
            x1[0] = d0 * invl_s[8*l8+0]; x2[0] = 0.5f * d0;
            x1[1] = d1 * invl_s[8*l8+1]; x2[1] = 0.5f * d1;
            x1[2] = d2 * invl_s[8*l8+2]; x2[2] = 0.5f * d2;
            x1[3] = d3 * invl_s[8*l8+3]; x2[3] = 0.5f * d3;
            x1[4] = d4 * invl_s[8*l8+4]; x2[4] = 0.5f * d4;
            x1[5] = d5 * invl_s[8*l8+5]; x2[5] = 0.5f * d5;
            x1[6] = d6 * invl_s[8*l8+6]; x2[6] = 0.5f * d6;
            x1[7] = d7 * invl_s[8*l8+7]; x2[7] = 0.5f * d7;
        }
        for (int k8 = 0; k8 < 8; ++k8) {
            #pragma unroll
            for (int kk = 0; kk < 8; ++kk) {
                const int k = 8 * k8 + kk;
                const int src = (lw & 56) | k8;
                float z1 = __shfl(x1[kk], src, 64);
                float z2 = __shfl(x2[kk], src, 64);
                #pragma unroll
                for (int s = 0; s < 8; ++s) {
                    x1[s] -= LmT1[k * STR + 8 * l8 + s] * z1;   // zero-filled rows
                    x2[s] -= LmT2[k * STR + 8 * l8 + s] * z2;
                }
            }
        }
        // phi from quadform of x1
        float qf = 0.f;
        #pragma unroll
        for (int s = 0; s < 8; ++s) qf += x1[s] * x1[s] * invd1[8 * l8 + s];
        qf += __shfl_xor(qf, 1, 64);
        qf += __shfl_xor(qf, 2, 64);
        qf += __shfl_xor(qf, 4, 64);
        float ph = expf(-0.5f * (logdet1 + qf));   // normalizer * exp_term
        phiw_s[grp * W9 + l8] = ph * w9_s[grp * W9 + l8];
        // H from x2
        #pragma unroll
        for (int s = 0; s < 8; ++s)
            H_s[grp * STR + 8 * l8 + s] = x2[s] * sqrtf(invd2[8 * l8 + s]);
    }
    __syncthreads();

    // ---- Gram / Q / U = Q w (all waves) ----
    {
        float acc[4] = {0.f, 0.f, 0.f, 0.f};
        const int rot = 2 * l8;   // per-lane column rotation: kills bank conflicts
        #pragma unroll 2
        for (int e = 0; e < 16; ++e) {
            const int e4 = 4 * ((e + rot) & 15);
            const float4 hn = *(const float4*)&H_s[grp * STR + e4];
            #pragma unroll
            for (int mm = 0; mm < 4; ++mm) {
                const float4 hm = *(const float4*)&H_s[(4 * l8 + mm) * STR + e4];
                float s0 = hn.x + hm.x, s1 = hn.y + hm.y;
                float s2 = hn.z + hm.z, s3 = hn.w + hm.w;
                acc[mm] += s0*s0 + s1*s1 + s2*s2 + s3*s3;   // |h_n+h_m|^2
            }
        }
        const float4 e1 = *(const float4*)&ws[grp * NN + 4 * l8];
        float Q0 = cq * expf(e1.x - 0.5f * acc[0]);
        float Q1 = cq * expf(e1.y - 0.5f * acc[1]);
        float Q2 = cq * expf(e1.z - 0.5f * acc[2]);
        float Q3 = cq * expf(e1.w - 0.5f * acc[3]);
        float u[8];
        #pragma unroll
        for (int a = 0; a < 8; ++a) {
            u[a] = Q0 * w9_s[(4*l8+0)*W9 + a] + Q1 * w9_s[(4*l8+1)*W9 + a]
                 + Q2 * w9_s[(4*l8+2)*W9 + a] + Q3 * w9_s[(4*l8+3)*W9 + a];
            u[a] += __shfl_xor(u[a], 1, 64);
            u[a] += __shfl_xor(u[a], 2, 64);
            u[a] += __shfl_xor(u[a], 4, 64);
        }
        float uv = (l8 == 0) ? u[0] : (l8 == 1) ? u[1] : (l8 == 2) ? u[2] : (l8 == 3) ? u[3]
                 : (l8 == 4) ? u[4] : (l8 == 5) ? u[5] : (l8 == 6) ? u[6] : u[7];
        U_s[grp * W9 + l8] = uv;   // U = Q w
    }
    // ---- K[d][a] = sum_n s_n[d] * phiw[n][a] (centers via L1) ----
    {
        const int d = t >> 2, a0 = (t & 3) * 2;
        const float md = mean_s[d], il = invl_s[d];
        float k0 = 0.f, k1 = 0.f;
        for (int n = 0; n < NN; ++n) {
            float sv = (centers[n * DD + d] - md) * il;
            k0 += sv * phiw_s[n * W9 + a0];
            k1 += sv * phiw_s[n * W9 + a0 + 1];
        }
        K_s[d * W9 + a0]     = k0;
        K_s[d * W9 + a0 + 1] = k1;
    }
    __syncthreads();

    // ---- parallel: wave0 solve B1^{-1}K (8 RHS) | amean | acr = w^T U ----
    if (t < 64) {
        const int aa = t >> 3;   // RHS index
        float y[8];
        #pragma unroll
        for (int s = 0; s < 8; ++s) y[s] = K_s[(8 * l8 + s) * W9 + aa];
        for (int k8 = 0; k8 < 8; ++k8) {              // forward (unit-L)
            #pragma unroll
            for (int kk = 0; kk < 8; ++kk) {
                const int k = 8 * k8 + kk;
                float zk = __shfl(y[kk], (t & 56) | k8, 64);
                #pragma unroll
                for (int s = 0; s < 8; ++s)
                    y[s] -= LmT1[k * STR + 8 * l8 + s] * zk;
            }
        }
        #pragma unroll
        for (int s = 0; s < 8; ++s) y[s] *= invd1[8 * l8 + s];
        // backward (L^T), dot-form: reads L^T ROWS (contiguous, conflict-free)
        for (int i8 = 7; i8 >= 0; --i8) {
            #pragma unroll
            for (int ii = 7; ii >= 0; --ii) {
                const int i = 8 * i8 + ii;
                const float4 r0 = *(const float4*)&LmT1[i * STR + 8 * l8];
                const float4 r1 = *(const float4*)&LmT1[i * STR + 8 * l8 + 4];
                float part = r0.x*y[0] + r0.y*y[1] + r0.z*y[2] + r0.w*y[3]
                           + r1.x*y[4] + r1.y*y[5] + r1.z*y[6] + r1.w*y[7];
                part += __shfl_xor(part, 1, 64);
                part += __shfl_xor(part, 2, 64);
                part += __shfl_xor(part, 4, 64);
                if (l8 == i8) y[ii] -= part;
            }
        }
        #pragma unroll
        for (int s = 0; s < 8; ++s)
            cp_s[(8 * l8 + s) * W9 + aa] = y[s] * invl_s[8 * l8 + s];
    } else if (t < 72) {
        int a = t - 64;
        float am = 0.f;
        for (int n = 0; n < NN; ++n) am += phiw_s[n * W9 + a];
        am_s[a] = am;
    } else if (t >= 128 && t < 192) {
        int t2 = t - 128, a = t2 >> 3, c = t2 & 7;
        float acc2 = 0.f;
        for (int n = 0; n < NN; ++n) acc2 += w9_s[n * W9 + a] * U_s[n * W9 + c];
        acr_s[a * W9 + c] = acc2;
    }
    __syncthreads();

    // ---- squash + outputs ----
    float* out0 = out;
    float* out1 = out + (size_t)NBATCH * AA;
    float* out2 = out + (size_t)NBATCH * AA + (size_t)NBATCH * AA * AA;
    if (t < 64) {
        const int a = t >> 3, c = t & 7;
        const float ama = am_s[a], amc = am_s[c];
        const float vac = 0.5f * (acr_s[a * W9 + c] + acr_s[c * W9 + a])
                        - ama * amc + ((a == c) ? 1e-6f : 0.0f);
        const float dca = acr_s[a * W9 + a] - ama * ama + 1e-6f;
        const float dcc = acr_s[c * W9 + c] - amc * amc + 1e-6f;
        const float q = expf(-0.5f * (dca + dcc));
        // expm1 formulation avoids catastrophic cancellation at vac ~ 1e-6
        const float sq = 0.5f * q * (expm1f(vac) * cosf(ama - amc)
                                   - expm1f(-vac) * cosf(ama + amc));
        out1[(size_t)b * 64 + t] = sq;
        if (t < AA) {
            float dct = acr_s[t * W9 + t] - am_s[t] * am_s[t] + 1e-6f;
            float e = expf(-0.5f * dct);
            out0[(size_t)b * AA + t] = e * sinf(am_s[t]);
            Ca_s[t] = e * cosf(am_s[t]);
        }
    }
    __syncthreads();
    #pragma unroll
    for (int e = 0; e < 2; ++e) {
        int idx = t + 256 * e;
        out2[(size_t)b * 512 + idx] = cp_s[(idx >> 3) * W9 + (idx & 7)] * Ca_s[idx & 7];
    }
}

extern "C" void kernel_launch(void* const* d_in, const int* in_sizes, int n_in,
                              void* d_out, int out_size, void* d_ws, size_t ws_size,
                              hipStream_t stream) {
    (void)in_sizes; (void)n_in; (void)out_size; (void)ws_size;
    const float* mean    = (const float*)d_in[0];
    const float* cov     = (const float*)d_in[1];
    const float* centers = (const float*)d_in[2];
    const float* weights = (const float*)d_in[3];
    const float* ls      = (const float*)d_in[4];
    float* ws = (float*)d_ws;
    float* o  = (float*)d_out;
    rbf_prep<<<4, 256, 0, stream>>>(centers, ls, ws);
    rbf_main<<<NBATCH, 256, 0, stream>>>(mean, cov, centers, weights, ls, ws, o);
}

// Round 7
// 218.386 us; speedup vs baseline: 2.5460x; 1.0586x over previous
//
#include <hip/hip_runtime.h>
#include <math.h>

// RBFController: B=2048, N=32 centers, D=64 dims, A=8 actions.
// One 256-thread block per batch element. Two SPD 64x64 LDL^T factorizations
// FUSED with SHIFTED OWNERSHIP: wave w owns M2 cols 16w.. and M1 cols
// 16*((w+2)&3).. , so per panel slot TWO DIFFERENT waves factor panel p of
// the two matrices in parallel. Trailing updates are SKIPPED wave-uniformly
// once a wave's columns are fully factored (zero-filled scheme otherwise
// wastes 2x FLOPs): M2 iff wv>=p+1, M1 iff ((wv+2)&3)>=p+1 — the factoring
// wave meets its condition with equality.
// Final phase: wave0 8-RHS solve runs CONCURRENTLY with waves1-3 Gram.
//
// VGPR/occupancy model (measured R1-R6): waves/SIMD = floor(256/VGPR_Count).
//   (256,4)->cap64: huge spills. uncapped: 164 VGPR -> 1 wave/SIMD.
//   (256,3)->cap85: 3 waves/SIMD, minor spills (WRITE ~13MB vs 4.8 real).

#define DD 64
#define NN 32
#define AA 8
#define NBATCH 2048
#define STR 68   // L^T / H row stride (words): 272 B, 16B-aligned rows
#define W9 9     // padded stride for N x A arrays (kills 8/16-way conflicts)

// ---------------- prep: exp1[n][m] table + logdet_lh scalar ----------------
__global__ void rbf_prep(const float* __restrict__ centers,
                         const float* __restrict__ ls,
                         float* __restrict__ ws) {
    __shared__ float cen_s[NN * DD];
    __shared__ float il2_s[DD];
    int t = threadIdx.x;
    for (int e = t; e < NN * DD; e += 256) cen_s[e] = centers[e];
    if (t < DD) { float l = ls[t]; il2_s[t] = 1.0f / (l * l); }
    __syncthreads();
    int p = blockIdx.x * 256 + t;
    if (p < NN * NN) {
        int n = p >> 5, m = p & 31;
        float acc = 0.f;
        for (int d = 0; d < DD; ++d) {
            float df = cen_s[n * DD + d] - cen_s[m * DD + d];
            acc += df * df * il2_s[d];
        }
        ws[p] = -0.25f * acc;              // exp1[n][m]
    }
    if (blockIdx.x == 0 && t < DD) {
        float l = ls[t];
        float v = logf(0.5f * l * l);
        #pragma unroll
        for (int o = 1; o < 64; o <<= 1) v += __shfl_xor(v, o, 64);
        if (t == 0) ws[NN * NN] = v;       // logdet_lh
    }
}

// Wave-local panel factorization. PRECONDITION: the executing wave owns
// cols 16p..16p+15 of A in its register tiles (lane lw: rows 4*(lw&15)..,
// panel-local col tile lw>>4). Pure shfl pivot exchange; writes zero-filled
// L^T rows to LDS. Ownership-shift invariant (panel-local indexing).
__device__ __forceinline__ void factor_panel(float (&A)[4][4], const int p,
    float* __restrict__ LmT, float* __restrict__ diag_s, float* __restrict__ invd_s,
    const int lw)
{
    const int rb  = lw & 15;
    const int cbl = lw >> 4;
    const int c0  = 16 * p + 4 * cbl;
    const int r0  = 4 * rb;
    #pragma unroll
    for (int jj = 0; jj < 16; ++jj) {
        const int q  = jj >> 2;
        const int ci = jj & 3;
        const int j  = 16 * p + jj;
        const int fsrc = rb | (q << 4);
        const int hsrc = (4 * p + cbl) | (q << 4);
        const int dsrc = (4 * p + q) | (q << 4);
        float d  = __shfl(A[ci][ci], dsrc, 64);
        float f0 = __shfl(A[0][ci], fsrc, 64);
        float f1 = __shfl(A[1][ci], fsrc, 64);
        float f2 = __shfl(A[2][ci], fsrc, 64);
        float f3 = __shfl(A[3][ci], fsrc, 64);
        float h0 = __shfl(A[0][ci], hsrc, 64);
        float h1 = __shfl(A[1][ci], hsrc, 64);
        float h2 = __shfl(A[2][ci], hsrc, 64);
        float h3 = __shfl(A[3][ci], hsrc, 64);
        float id = __builtin_amdgcn_rcpf(d);   // cond(A) ~ 1; ~1ulp fine
        float fr[4];
        fr[0] = (r0 + 0 > j) ? f0 : 0.f;
        fr[1] = (r0 + 1 > j) ? f1 : 0.f;
        fr[2] = (r0 + 2 > j) ? f2 : 0.f;
        fr[3] = (r0 + 3 > j) ? f3 : 0.f;
        float hc[4];
        hc[0] = (c0 + 0 > j) ? h0 * id : 0.f;
        hc[1] = (c0 + 1 > j) ? h1 * id : 0.f;
        hc[2] = (c0 + 2 > j) ? h2 * id : 0.f;
        hc[3] = (c0 + 3 > j) ? h3 * id : 0.f;
        #pragma unroll
        for (int s = 0; s < 4; ++s)
            #pragma unroll
            for (int c = 0; c < 4; ++c)
                A[s][c] -= fr[s] * hc[c];
        if (cbl == 0) {
            float4 v = make_float4(fr[0] * id, fr[1] * id, fr[2] * id, fr[3] * id);
            *(float4*)&LmT[j * STR + r0] = v;
        }
        if (lw == jj) { diag_s[j] = d; invd_s[j] = id; }
    }
}

// Rank-16 trailing update, single matrix. Zero-filled L^T rows auto-mask <=k.
__device__ __forceinline__ void trailing_one(float (&A)[4][4], const int p,
    const float* __restrict__ LmT, const float* __restrict__ diag_s,
    const int rb, const int cbX)
{
    #pragma unroll 2
    for (int kk = 0; kk < 16; ++kk) {
        const int k = 16 * p + kk;
        const float4 Lr = *(const float4*)&LmT[k * STR + 4 * rb];
        const float4 Lc = *(const float4*)&LmT[k * STR + 4 * cbX];
        const float dk = diag_s[k];
        const float h0 = Lc.x * dk, h1 = Lc.y * dk, h2 = Lc.z * dk, h3 = Lc.w * dk;
        A[0][0] -= Lr.x * h0; A[0][1] -= Lr.x * h1; A[0][2] -= Lr.x * h2; A[0][3] -= Lr.x * h3;
        A[1][0] -= Lr.y * h0; A[1][1] -= Lr.y * h1; A[1][2] -= Lr.y * h2; A[1][3] -= Lr.y * h3;
        A[2][0] -= Lr.z * h0; A[2][1] -= Lr.z * h1; A[2][2] -= Lr.z * h2; A[2][3] -= Lr.z * h3;
        A[3][0] -= Lr.w * h0; A[3][1] -= Lr.w * h1; A[3][2] -= Lr.w * h2; A[3][3] -= Lr.w * h3;
    }
}

__global__ __launch_bounds__(256, 3) void rbf_main(
    const float* __restrict__ mean,      // (B,64)
    const float* __restrict__ cov,       // (B,64,64)
    const float* __restrict__ centers,   // (32,64)
    const float* __restrict__ weights,   // (32,8)
    const float* __restrict__ ls,        // (64,)
    const float* __restrict__ ws,        // exp1[1024], logdet_lh at [1024]
    float* __restrict__ out)
{
    __shared__ __align__(16) float LmT1[DD * STR];  // 17408 B  L1^T (M1)
    __shared__ __align__(16) float LmT2[DD * STR];  // 17408 B  L2^T (M2)
    __shared__ __align__(16) float H_s[NN * STR];   // 8704 B
    __shared__ __align__(16) float K_s[DD * W9];    // 2304 B
    __shared__ __align__(16) float cp_s[DD * W9];   // 2304 B
    __shared__ float diag1[DD], invd1[DD], diag2[DD], invd2[DD];
    __shared__ float mean_s[DD], invl_s[DD], l2h_s[DD];
    __shared__ float w9_s[NN * W9], phiw_s[NN * W9], U_s[NN * W9];
    __shared__ float am_s[AA], acr_s[AA * W9], Ca_s[AA];
    __shared__ float ldlh_s;
    // total ~53.7 KB -> 3 blocks/CU

    const int t   = threadIdx.x;
    const int b   = blockIdx.x;
    const int lw  = t & 63;
    const int wv  = t >> 6;
    const int rb  = t & 15;            // row tile (rows 4rb..4rb+3), both matrices
    const int cb  = t >> 4;            // M2 col tile; wave w owns M2 cols 16w..16w+15
    const int cb1 = (cb + 8) & 15;     // M1 col tile; wave w owns M1 panel (w+2)&3
    const int wp1 = (wv + 2) & 3;      // M1 panel owned by this wave
    const int grp = t >> 3;            // RHS group 0..31 in solves
    const int l8  = t & 7;             // lane-in-group (rows 8*l8..8*l8+7)
    const float* cvb = cov + (size_t)b * DD * DD;

    // ---- stage small arrays ----
    if (t < DD) {
        float l = ls[t];
        invl_s[t] = 1.0f / l;
        l2h_s[t]  = 0.5f * l * l;
        mean_s[t] = mean[(size_t)b * DD + t];
    }
    w9_s[(t >> 3) * W9 + (t & 7)] = weights[t];
    if (t == 0) ldlh_s = ws[NN * NN];
    __syncthreads();

    // ---- build tiles: A2 at (4rb, 4cb), A1 at (4rb, 4cb1) — symmetric loads
    float A1[4][4], A2[4][4];
    {
        #pragma unroll
        for (int c = 0; c < 4; ++c) {
            const int gr = 4 * cb + c;   // read row gr, cols 4rb.. (coalesced)
            const float4 cv = *(const float4*)(cvb + (size_t)gr * DD + 4 * rb);
            A2[0][c] = cv.x + ((4*rb+0 == gr) ? l2h_s[gr] : 0.0f);
            A2[1][c] = cv.y + ((4*rb+1 == gr) ? l2h_s[gr] : 0.0f);
            A2[2][c] = cv.z + ((4*rb+2 == gr) ? l2h_s[gr] : 0.0f);
            A2[3][c] = cv.w + ((4*rb+3 == gr) ? l2h_s[gr] : 0.0f);
        }
        const float il0 = invl_s[4*rb+0], il1 = invl_s[4*rb+1],
                    il2 = invl_s[4*rb+2], il3 = invl_s[4*rb+3];
        #pragma unroll
        for (int c = 0; c < 4; ++c) {
            const int gr = 4 * cb1 + c;  // shifted cols for M1
            const float4 cv = *(const float4*)(cvb + (size_t)gr * DD + 4 * rb);
            const float ilc = invl_s[gr];
            A1[0][c] = cv.x * il0 * ilc + ((4*rb+0 == gr) ? 1.0f : 0.0f);
            A1[1][c] = cv.y * il1 * ilc + ((4*rb+1 == gr) ? 1.0f : 0.0f);
            A1[2][c] = cv.z * il2 * ilc + ((4*rb+2 == gr) ? 1.0f : 0.0f);
            A1[3][c] = cv.w * il3 * ilc + ((4*rb+3 == gr) ? 1.0f : 0.0f);
        }
    }

    // ---- FUSED factorization with wave-uniform trailing skip ----
    if (wv == 0) factor_panel(A2, 0, LmT2, diag2, invd2, lw);
    if (wv == 2) factor_panel(A1, 0, LmT1, diag1, invd1, lw);
    #pragma unroll 1
    for (int p = 0; p < 3; ++p) {
        __syncthreads();
        if (wv  >= p + 1) trailing_one(A2, p, LmT2, diag2, rb, cb);
        if (wp1 >= p + 1) trailing_one(A1, p, LmT1, diag1, rb, cb1);
        if (wv == p + 1)         factor_panel(A2, p + 1, LmT2, diag2, invd2, lw);
        if (wv == ((p + 3) & 3)) factor_panel(A1, p + 1, LmT1, diag1, invd1, lw);
    }
    __syncthreads();

    // ---- per-wave logdets (redundant across waves; no barrier needed) ----
    float logdet1, cq;
    {
        float v1 = logf(diag1[lw]);
        float v2 = logf(diag2[lw]);
        #pragma unroll
        for (int o = 1; o < 64; o <<= 1) {
            v1 += __shfl_xor(v1, o, 64);
            v2 += __shfl_xor(v2, o, 64);
        }
        logdet1 = v1;
        cq = expf(0.5f * (ldlh_s - v2));
    }

    // ---- FUSED forward solves (32 RHS each): x1 -> phi, x2 -> H ----
    {
        float x1[8], x2[8];
        const float4 ca  = *(const float4*)(centers + grp * DD + 8 * l8);
        const float4 cb4 = *(const float4*)(centers + grp * DD + 8 * l8 + 4);
        {
            float d0 = ca.x  - mean_s[8*l8+0], d1 = ca.y  - mean_s[8*l8+1];
            float d2 = ca.z  - mean_s[8*l8+2], d3 = ca.w  - mean_s[8*l8+3];
            float d4 = cb4.x - mean_s[8*l8+4], d5 = cb4.y - mean_s[8*l8+5];
            float d6 = cb4.z - mean_s[8*l8+6], d7 = cb4.w - mean_s[8*l8+7];
            x1[0] = d0 * invl_s[8*l8+0]; x2[0] = 0.5f * d0;
            x1[1] = d1 * invl_s[8*l8+1]; x2[1] = 0.5f * d1;
            x1[2] = d2 * invl_s[8*l8+2]; x2[2] = 0.5f * d2;
            x1[3] = d3 * invl_s[8*l8+3]; x2[3] = 0.5f * d3;
            x1[4] = d4 * invl_s[8*l8+4]; x2[4] = 0.5f * d4;
            x1[5] = d5 * invl_s[8*l8+5]; x2[5] = 0.5f * d5;
            x1[6] = d6 * invl_s[8*l8+6]; x2[6] = 0.5f * d6;
            x1[7] = d7 * invl_s[8*l8+7]; x2[7] = 0.5f * d7;
        }
        for (int k8 = 0; k8 < 8; ++k8) {
            #pragma unroll
            for (int kk = 0; kk < 8; ++kk) {
                const int k = 8 * k8 + kk;
                const int src = (lw & 56) | k8;
                float z1 = __shfl(x1[kk], src, 64);
                float z2 = __shfl(x2[kk], src, 64);
                #pragma unroll
                for (int s = 0; s < 8; ++s) {
                    x1[s] -= LmT1[k * STR + 8 * l8 + s] * z1;   // zero-filled rows
                    x2[s] -= LmT2[k * STR + 8 * l8 + s] * z2;
                }
            }
        }
        // phi from quadform of x1
        float qf = 0.f;
        #pragma unroll
        for (int s = 0; s < 8; ++s) qf += x1[s] * x1[s] * invd1[8 * l8 + s];
        qf += __shfl_xor(qf, 1, 64);
        qf += __shfl_xor(qf, 2, 64);
        qf += __shfl_xor(qf, 4, 64);
        float ph = expf(-0.5f * (logdet1 + qf));   // normalizer * exp_term
        phiw_s[grp * W9 + l8] = ph * w9_s[grp * W9 + l8];
        // H from x2
        #pragma unroll
        for (int s = 0; s < 8; ++s)
            H_s[grp * STR + 8 * l8 + s] = x2[s] * sqrtf(invd2[8 * l8 + s]);
    }
    __syncthreads();

    // ---- phase A: K build (t<128) + amean (t in [128,136)) ----
    if (t < 128) {
        const int d = t >> 1, a0 = (t & 1) * 4;
        const float md = mean_s[d], il = invl_s[d];
        float k0 = 0.f, k1 = 0.f, k2 = 0.f, k3 = 0.f;
        for (int n = 0; n < NN; ++n) {
            float sv = (centers[n * DD + d] - md) * il;
            k0 += sv * phiw_s[n * W9 + a0];
            k1 += sv * phiw_s[n * W9 + a0 + 1];
            k2 += sv * phiw_s[n * W9 + a0 + 2];
            k3 += sv * phiw_s[n * W9 + a0 + 3];
        }
        K_s[d * W9 + a0]     = k0;
        K_s[d * W9 + a0 + 1] = k1;
        K_s[d * W9 + a0 + 2] = k2;
        K_s[d * W9 + a0 + 3] = k3;
    } else if (t < 136) {
        int a = t - 128;
        float am = 0.f;
        for (int n = 0; n < NN; ++n) am += phiw_s[n * W9 + a];
        am_s[a] = am;
    }
    __syncthreads();

    // ---- phase B: wave0 8-RHS solve  ||  waves1-3 Gram/Q/U ----
    if (wv == 0) {
        const int aa = t >> 3;   // RHS index
        float y[8];
        #pragma unroll
        for (int s = 0; s < 8; ++s) y[s] = K_s[(8 * l8 + s) * W9 + aa];
        for (int k8 = 0; k8 < 8; ++k8) {              // forward (unit-L)
            #pragma unroll
            for (int kk = 0; kk < 8; ++kk) {
                const int k = 8 * k8 + kk;
                float zk = __shfl(y[kk], (t & 56) | k8, 64);
                #pragma unroll
                for (int s = 0; s < 8; ++s)
                    y[s] -= LmT1[k * STR + 8 * l8 + s] * zk;
            }
        }
        #pragma unroll
        for (int s = 0; s < 8; ++s) y[s] *= invd1[8 * l8 + s];
        // backward (L^T), dot-form: reads L^T ROWS (contiguous, conflict-free)
        for (int i8 = 7; i8 >= 0; --i8) {
            #pragma unroll
            for (int ii = 7; ii >= 0; --ii) {
                const int i = 8 * i8 + ii;
                const float4 r0 = *(const float4*)&LmT1[i * STR + 8 * l8];
                const float4 r1 = *(const float4*)&LmT1[i * STR + 8 * l8 + 4];
                float part = r0.x*y[0] + r0.y*y[1] + r0.z*y[2] + r0.w*y[3]
                           + r1.x*y[4] + r1.y*y[5] + r1.z*y[6] + r1.w*y[7];
                part += __shfl_xor(part, 1, 64);
                part += __shfl_xor(part, 2, 64);
                part += __shfl_xor(part, 4, 64);
                if (l8 == i8) y[ii] -= part;
            }
        }
        #pragma unroll
        for (int s = 0; s < 8; ++s)
            cp_s[(8 * l8 + s) * W9 + aa] = y[s] * invl_s[8 * l8 + s];
    } else {
        const int g = (t - 64) >> 3;   // group 0..23; rows g and g+24 (g<8)
        for (int n = g; n < NN; n += 24) {
            float acc[4] = {0.f, 0.f, 0.f, 0.f};
            const int rot = 2 * l8;   // per-lane column rotation: kills bank conflicts
            #pragma unroll 2
            for (int e = 0; e < 16; ++e) {
                const int e4 = 4 * ((e + rot) & 15);
                const float4 hn = *(const float4*)&H_s[n * STR + e4];
                #pragma unroll
                for (int mm = 0; mm < 4; ++mm) {
                    const float4 hm = *(const float4*)&H_s[(4 * l8 + mm) * STR + e4];
                    float s0 = hn.x + hm.x, s1 = hn.y + hm.y;
                    float s2 = hn.z + hm.z, s3 = hn.w + hm.w;
                    acc[mm] += s0*s0 + s1*s1 + s2*s2 + s3*s3;   // |h_n+h_m|^2
                }
            }
            const float4 e1 = *(const float4*)&ws[n * NN + 4 * l8];
            float Q0 = cq * expf(e1.x - 0.5f * acc[0]);
            float Q1 = cq * expf(e1.y - 0.5f * acc[1]);
            float Q2 = cq * expf(e1.z - 0.5f * acc[2]);
            float Q3 = cq * expf(e1.w - 0.5f * acc[3]);
            float u[8];
            #pragma unroll
            for (int a = 0; a < 8; ++a) {
                u[a] = Q0 * w9_s[(4*l8+0)*W9 + a] + Q1 * w9_s[(4*l8+1)*W9 + a]
                     + Q2 * w9_s[(4*l8+2)*W9 + a] + Q3 * w9_s[(4*l8+3)*W9 + a];
                u[a] += __shfl_xor(u[a], 1, 64);
                u[a] += __shfl_xor(u[a], 2, 64);
                u[a] += __shfl_xor(u[a], 4, 64);
            }
            float uv = (l8 == 0) ? u[0] : (l8 == 1) ? u[1] : (l8 == 2) ? u[2] : (l8 == 3) ? u[3]
                     : (l8 == 4) ? u[4] : (l8 == 5) ? u[5] : (l8 == 6) ? u[6] : u[7];
            U_s[n * W9 + l8] = uv;   // U = Q w
        }
    }
    __syncthreads();

    // ---- phase C: acr = w^T U ----
    if (t < 64) {
        const int a = t >> 3, c = t & 7;
        float acc2 = 0.f;
        for (int n = 0; n < NN; ++n) acc2 += w9_s[n * W9 + a] * U_s[n * W9 + c];
        acr_s[a * W9 + c] = acc2;
    }
    __syncthreads();

    // ---- squash + outputs ----
    float* out0 = out;
    float* out1 = out + (size_t)NBATCH * AA;
    float* out2 = out + (size_t)NBATCH * AA + (size_t)NBATCH * AA * AA;
    if (t < 64) {
        const int a = t >> 3, c = t & 7;
        const float ama = am_s[a], amc = am_s[c];
        const float vac = 0.5f * (acr_s[a * W9 + c] + acr_s[c * W9 + a])
                        - ama * amc + ((a == c) ? 1e-6f : 0.0f);
        const float dca = acr_s[a * W9 + a] - ama * ama + 1e-6f;
        const float dcc = acr_s[c * W9 + c] - amc * amc + 1e-6f;
        const float q = expf(-0.5f * (dca + dcc));
        // expm1 formulation avoids catastrophic cancellation at vac ~ 1e-6
        const float sq = 0.5f * q * (expm1f(vac) * cosf(ama - amc)
                                   - expm1f(-vac) * cosf(ama + amc));
        out1[(size_t)b * 64 + t] = sq;
        if (t < AA) {
            float dct = acr_s[t * W9 + t] - am_s[t] * am_s[t] + 1e-6f;
            float e = expf(-0.5f * dct);
            out0[(size_t)b * AA + t] = e * sinf(am_s[t]);
            Ca_s[t] = e * cosf(am_s[t]);
        }
    }
    __syncthreads();
    #pragma unroll
    for (int e = 0; e < 2; ++e) {
        int idx = t + 256 * e;
        out2[(size_t)b * 512 + idx] = cp_s[(idx >> 3) * W9 + (idx & 7)] * Ca_s[idx & 7];
    }
}

extern "C" void kernel_launch(void* const* d_in, const int* in_sizes, int n_in,
                              void* d_out, int out_size, void* d_ws, size_t ws_size,
                              hipStream_t stream) {
    (void)in_sizes; (void)n_in; (void)out_size; (void)ws_size;
    const float* mean    = (const float*)d_in[0];
    const float* cov     = (const float*)d_in[1];
    const float* centers = (const float*)d_in[2];
    const float* weights = (const float*)d_in[3];
    const float* ls      = (const float*)d_in[4];
    float* ws = (float*)d_ws;
    float* o  = (float*)d_out;
    rbf_prep<<<4, 256, 0, stream>>>(centers, ls, ws);
    rbf_main<<<NBATCH, 256, 0, stream>>>(mean, cov, centers, weights, ls, ws, o);
}

// Round 8
// 217.575 us; speedup vs baseline: 2.5555x; 1.0037x over previous
//
#include <hip/hip_runtime.h>
#include <math.h>

// RBFController: B=2048, N=32 centers, D=64 dims, A=8 actions.
// One 256-thread block per batch element. LDS-throughput-bound (R7 model:
// ~40k LDS-pipe cyc/block x 8 blocks/CU ~= measured 149us). This round cuts
// LDS instructions: (1) fused forward solves use 2 RHS/lane on 2 waves only
// (L-row reads are shared by all RHS in a wave -> half the b128s);
// (2) Gram 2-row blocking (6 b128/e for 2 rows vs 10); (3) freed waves run
// K-build+cp-solve / amean concurrently. All FP sequences bitwise identical
// to R7 (absmax margin 1.49e-8 vs 2.03e-8 threshold is too thin to touch).
//
// VGPR/occupancy model (measured): waves/SIMD = floor(256/VGPR_Count).
// (256,3)->cap85 -> 3 waves/SIMD; LDS 53.7KB -> 3 blocks/CU.

#define DD 64
#define NN 32
#define AA 8
#define NBATCH 2048
#define STR 68   // L^T / H row stride (words): 272 B, 16B-aligned rows
#define W9 9     // padded stride (kills stride-32-word bank hazards)

// ---------------- prep: exp1[n][m] table + logdet_lh scalar ----------------
__global__ void rbf_prep(const float* __restrict__ centers,
                         const float* __restrict__ ls,
                         float* __restrict__ ws) {
    __shared__ float cen_s[NN * DD];
    __shared__ float il2_s[DD];
    int t = threadIdx.x;
    for (int e = t; e < NN * DD; e += 256) cen_s[e] = centers[e];
    if (t < DD) { float l = ls[t]; il2_s[t] = 1.0f / (l * l); }
    __syncthreads();
    int p = blockIdx.x * 256 + t;
    if (p < NN * NN) {
        int n = p >> 5, m = p & 31;
        float acc = 0.f;
        for (int d = 0; d < DD; ++d) {
            float df = cen_s[n * DD + d] - cen_s[m * DD + d];
            acc += df * df * il2_s[d];
        }
        ws[p] = -0.25f * acc;              // exp1[n][m]
    }
    if (blockIdx.x == 0 && t < DD) {
        float l = ls[t];
        float v = logf(0.5f * l * l);
        #pragma unroll
        for (int o = 1; o < 64; o <<= 1) v += __shfl_xor(v, o, 64);
        if (t == 0) ws[NN * NN] = v;       // logdet_lh
    }
}

// Wave-local panel factorization. PRECONDITION: executing wave owns cols
// 16p..16p+15 of A (lane lw: rows 4*(lw&15).., panel-local col tile lw>>4).
__device__ __forceinline__ void factor_panel(float (&A)[4][4], const int p,
    float* __restrict__ LmT, float* __restrict__ diag_s, float* __restrict__ invd_s,
    const int lw)
{
    const int rb  = lw & 15;
    const int cbl = lw >> 4;
    const int c0  = 16 * p + 4 * cbl;
    const int r0  = 4 * rb;
    #pragma unroll
    for (int jj = 0; jj < 16; ++jj) {
        const int q  = jj >> 2;
        const int ci = jj & 3;
        const int j  = 16 * p + jj;
        const int fsrc = rb | (q << 4);
        const int hsrc = (4 * p + cbl) | (q << 4);
        const int dsrc = (4 * p + q) | (q << 4);
        float d  = __shfl(A[ci][ci], dsrc, 64);
        float f0 = __shfl(A[0][ci], fsrc, 64);
        float f1 = __shfl(A[1][ci], fsrc, 64);
        float f2 = __shfl(A[2][ci], fsrc, 64);
        float f3 = __shfl(A[3][ci], fsrc, 64);
        float h0 = __shfl(A[0][ci], hsrc, 64);
        float h1 = __shfl(A[1][ci], hsrc, 64);
        float h2 = __shfl(A[2][ci], hsrc, 64);
        float h3 = __shfl(A[3][ci], hsrc, 64);
        float id = __builtin_amdgcn_rcpf(d);   // cond(A) ~ 1; ~1ulp fine
        float fr[4];
        fr[0] = (r0 + 0 > j) ? f0 : 0.f;
        fr[1] = (r0 + 1 > j) ? f1 : 0.f;
        fr[2] = (r0 + 2 > j) ? f2 : 0.f;
        fr[3] = (r0 + 3 > j) ? f3 : 0.f;
        float hc[4];
        hc[0] = (c0 + 0 > j) ? h0 * id : 0.f;
        hc[1] = (c0 + 1 > j) ? h1 * id : 0.f;
        hc[2] = (c0 + 2 > j) ? h2 * id : 0.f;
        hc[3] = (c0 + 3 > j) ? h3 * id : 0.f;
        #pragma unroll
        for (int s = 0; s < 4; ++s)
            #pragma unroll
            for (int c = 0; c < 4; ++c)
                A[s][c] -= fr[s] * hc[c];
        if (cbl == 0) {
            float4 v = make_float4(fr[0] * id, fr[1] * id, fr[2] * id, fr[3] * id);
            *(float4*)&LmT[j * STR + r0] = v;
        }
        if (lw == jj) { diag_s[j] = d; invd_s[j] = id; }
    }
}

// Rank-16 trailing update, single matrix. Zero-filled L^T rows auto-mask <=k.
__device__ __forceinline__ void trailing_one(float (&A)[4][4], const int p,
    const float* __restrict__ LmT, const float* __restrict__ diag_s,
    const int rb, const int cbX)
{
    #pragma unroll 2
    for (int kk = 0; kk < 16; ++kk) {
        const int k = 16 * p + kk;
        const float4 Lr = *(const float4*)&LmT[k * STR + 4 * rb];
        const float4 Lc = *(const float4*)&LmT[k * STR + 4 * cbX];
        const float dk = diag_s[k];
        const float h0 = Lc.x * dk, h1 = Lc.y * dk, h2 = Lc.z * dk, h3 = Lc.w * dk;
        A[0][0] -= Lr.x * h0; A[0][1] -= Lr.x * h1; A[0][2] -= Lr.x * h2; A[0][3] -= Lr.x * h3;
        A[1][0] -= Lr.y * h0; A[1][1] -= Lr.y * h1; A[1][2] -= Lr.y * h2; A[1][3] -= Lr.y * h3;
        A[2][0] -= Lr.z * h0; A[2][1] -= Lr.z * h1; A[2][2] -= Lr.z * h2; A[2][3] -= Lr.z * h3;
        A[3][0] -= Lr.w * h0; A[3][1] -= Lr.w * h1; A[3][2] -= Lr.w * h2; A[3][3] -= Lr.w * h3;
    }
}

__global__ __launch_bounds__(256, 3) void rbf_main(
    const float* __restrict__ mean,      // (B,64)
    const float* __restrict__ cov,       // (B,64,64)
    const float* __restrict__ centers,   // (32,64)
    const float* __restrict__ weights,   // (32,8)
    const float* __restrict__ ls,        // (64,)
    const float* __restrict__ ws,        // exp1[1024], logdet_lh at [1024]
    float* __restrict__ out)
{
    __shared__ __align__(16) float LmT1[DD * STR];  // 17408 B  L1^T (M1)
    __shared__ __align__(16) float LmT2[DD * STR];  // 17408 B  L2^T (M2)
    __shared__ __align__(16) float H_s[NN * STR];   // 8704 B
    __shared__ __align__(16) float K_s[DD * W9];    // 2304 B
    __shared__ __align__(16) float cp_s[DD * W9];   // 2304 B
    __shared__ __align__(16) float phiwc[NN * AA];  // 1024 B compact (b128 reads)
    __shared__ float diag1[DD], invd1[DD], diag2[DD], invd2[DD];
    __shared__ float mean_s[DD], invl_s[DD], l2h_s[DD];
    __shared__ float w9_s[NN * W9], U_s[NN * W9];
    __shared__ float am_s[AA], acr_s[AA * W9], Ca_s[AA];
    __shared__ float ldlh_s;
    // total ~53.6 KB -> 3 blocks/CU

    const int t   = threadIdx.x;
    const int b   = blockIdx.x;
    const int lw  = t & 63;
    const int wv  = t >> 6;
    const int rb  = t & 15;            // row tile (rows 4rb..4rb+3), both matrices
    const int cb  = t >> 4;            // M2 col tile; wave w owns M2 cols 16w..16w+15
    const int cb1 = (cb + 8) & 15;     // M1 col tile; wave w owns M1 panel (w+2)&3
    const int wp1 = (wv + 2) & 3;      // M1 panel owned by this wave
    const int l8  = t & 7;             // lane-in-group (rows 8*l8..8*l8+7)
    const float* cvb = cov + (size_t)b * DD * DD;

    // ---- stage small arrays ----
    if (t < DD) {
        float l = ls[t];
        invl_s[t] = 1.0f / l;
        l2h_s[t]  = 0.5f * l * l;
        mean_s[t] = mean[(size_t)b * DD + t];
    }
    w9_s[(t >> 3) * W9 + (t & 7)] = weights[t];
    if (t == 0) ldlh_s = ws[NN * NN];
    __syncthreads();

    // ---- build tiles: A2 at (4rb, 4cb), A1 at (4rb, 4cb1) — symmetric loads
    float A1[4][4], A2[4][4];
    {
        #pragma unroll
        for (int c = 0; c < 4; ++c) {
            const int gr = 4 * cb + c;
            const float4 cv = *(const float4*)(cvb + (size_t)gr * DD + 4 * rb);
            A2[0][c] = cv.x + ((4*rb+0 == gr) ? l2h_s[gr] : 0.0f);
            A2[1][c] = cv.y + ((4*rb+1 == gr) ? l2h_s[gr] : 0.0f);
            A2[2][c] = cv.z + ((4*rb+2 == gr) ? l2h_s[gr] : 0.0f);
            A2[3][c] = cv.w + ((4*rb+3 == gr) ? l2h_s[gr] : 0.0f);
        }
        const float il0 = invl_s[4*rb+0], il1 = invl_s[4*rb+1],
                    il2 = invl_s[4*rb+2], il3 = invl_s[4*rb+3];
        #pragma unroll
        for (int c = 0; c < 4; ++c) {
            const int gr = 4 * cb1 + c;
            const float4 cv = *(const float4*)(cvb + (size_t)gr * DD + 4 * rb);
            const float ilc = invl_s[gr];
            A1[0][c] = cv.x * il0 * ilc + ((4*rb+0 == gr) ? 1.0f : 0.0f);
            A1[1][c] = cv.y * il1 * ilc + ((4*rb+1 == gr) ? 1.0f : 0.0f);
            A1[2][c] = cv.z * il2 * ilc + ((4*rb+2 == gr) ? 1.0f : 0.0f);
            A1[3][c] = cv.w * il3 * ilc + ((4*rb+3 == gr) ? 1.0f : 0.0f);
        }
    }

    // ---- FUSED factorization with wave-uniform trailing skip ----
    if (wv == 0) factor_panel(A2, 0, LmT2, diag2, invd2, lw);
    if (wv == 2) factor_panel(A1, 0, LmT1, diag1, invd1, lw);
    #pragma unroll 1
    for (int p = 0; p < 3; ++p) {
        __syncthreads();
        if (wv  >= p + 1) trailing_one(A2, p, LmT2, diag2, rb, cb);
        if (wp1 >= p + 1) trailing_one(A1, p, LmT1, diag1, rb, cb1);
        if (wv == p + 1)         factor_panel(A2, p + 1, LmT2, diag2, invd2, lw);
        if (wv == ((p + 3) & 3)) factor_panel(A1, p + 1, LmT1, diag1, invd1, lw);
    }
    __syncthreads();

    // ---- per-wave logdets (redundant; no barrier needed) ----
    float logdet1, cq;
    {
        float v1 = logf(diag1[lw]);
        float v2 = logf(diag2[lw]);
        #pragma unroll
        for (int o = 1; o < 64; o <<= 1) {
            v1 += __shfl_xor(v1, o, 64);
            v2 += __shfl_xor(v2, o, 64);
        }
        logdet1 = v1;
        cq = expf(0.5f * (ldlh_s - v2));
    }

    // ---- phase S: waves 0,1 fused forward solves, 2 RHS/lane ----
    // L-row reads are identical across a wave's RHS -> 2 RHS/lane costs zero
    // extra LDS. Wave w handles RHS [16w, 16w+16): a = 16w+gr, b = a+8.
    if (wv < 2) {
        const int gr8 = lw >> 3;
        const int ra = 16 * wv + gr8;
        const int rz = ra + 8;
        float x1a[8], x2a[8], x1b[8], x2b[8];
        {
            const float4 ca0 = *(const float4*)(centers + ra * DD + 8 * l8);
            const float4 ca1 = *(const float4*)(centers + ra * DD + 8 * l8 + 4);
            const float4 cb0 = *(const float4*)(centers + rz * DD + 8 * l8);
            const float4 cb1v = *(const float4*)(centers + rz * DD + 8 * l8 + 4);
            float da[8] = {ca0.x,ca0.y,ca0.z,ca0.w,ca1.x,ca1.y,ca1.z,ca1.w};
            float db[8] = {cb0.x,cb0.y,cb0.z,cb0.w,cb1v.x,cb1v.y,cb1v.z,cb1v.w};
            #pragma unroll
            for (int s = 0; s < 8; ++s) {
                const int i = 8 * l8 + s;
                float d1 = da[s] - mean_s[i];
                float d2 = db[s] - mean_s[i];
                x1a[s] = d1 * invl_s[i]; x2a[s] = 0.5f * d1;
                x1b[s] = d2 * invl_s[i]; x2b[s] = 0.5f * d2;
            }
        }
        for (int k8 = 0; k8 < 8; ++k8) {
            #pragma unroll
            for (int kk = 0; kk < 8; ++kk) {
                const int k = 8 * k8 + kk;
                const int src = (lw & 56) | k8;
                float z1a = __shfl(x1a[kk], src, 64);
                float z1b = __shfl(x1b[kk], src, 64);
                float z2a = __shfl(x2a[kk], src, 64);
                float z2b = __shfl(x2b[kk], src, 64);
                const float4 LA = *(const float4*)&LmT1[k * STR + 8 * l8];
                const float4 LB = *(const float4*)&LmT1[k * STR + 8 * l8 + 4];
                const float4 MA = *(const float4*)&LmT2[k * STR + 8 * l8];
                const float4 MB = *(const float4*)&LmT2[k * STR + 8 * l8 + 4];
                float l1[8] = {LA.x,LA.y,LA.z,LA.w,LB.x,LB.y,LB.z,LB.w};
                float l2[8] = {MA.x,MA.y,MA.z,MA.w,MB.x,MB.y,MB.z,MB.w};
                #pragma unroll
                for (int s = 0; s < 8; ++s) {
                    x1a[s] -= l1[s] * z1a;
                    x1b[s] -= l1[s] * z1b;
                    x2a[s] -= l2[s] * z2a;
                    x2b[s] -= l2[s] * z2b;
                }
            }
        }
        float qfa = 0.f, qfb = 0.f;
        #pragma unroll
        for (int s = 0; s < 8; ++s) {
            qfa += x1a[s] * x1a[s] * invd1[8 * l8 + s];
            qfb += x1b[s] * x1b[s] * invd1[8 * l8 + s];
        }
        qfa += __shfl_xor(qfa, 1, 64); qfa += __shfl_xor(qfa, 2, 64); qfa += __shfl_xor(qfa, 4, 64);
        qfb += __shfl_xor(qfb, 1, 64); qfb += __shfl_xor(qfb, 2, 64); qfb += __shfl_xor(qfb, 4, 64);
        float pha = expf(-0.5f * (logdet1 + qfa));
        float phb = expf(-0.5f * (logdet1 + qfb));
        phiwc[ra * AA + l8] = pha * w9_s[ra * W9 + l8];
        phiwc[rz * AA + l8] = phb * w9_s[rz * W9 + l8];
        {
            float ha[8], hb[8];
            #pragma unroll
            for (int s = 0; s < 8; ++s) {
                const float rs = sqrtf(invd2[8 * l8 + s]);
                ha[s] = x2a[s] * rs;
                hb[s] = x2b[s] * rs;
            }
            *(float4*)&H_s[ra * STR + 8 * l8]     = make_float4(ha[0],ha[1],ha[2],ha[3]);
            *(float4*)&H_s[ra * STR + 8 * l8 + 4] = make_float4(ha[4],ha[5],ha[6],ha[7]);
            *(float4*)&H_s[rz * STR + 8 * l8]     = make_float4(hb[0],hb[1],hb[2],hb[3]);
            *(float4*)&H_s[rz * STR + 8 * l8 + 4] = make_float4(hb[4],hb[5],hb[6],hb[7]);
        }
    }
    __syncthreads();

    // ---- phase T: wave0 K-build + cp-solve | waves1,2 Gram pairs | wave3 amean
    if (wv == 0) {
        {   // K[d][a] = sum_n s_n[d] * phiw[n][a]; d = lane, all 8 a
            const int d = lw;
            const float md = mean_s[d], il = invl_s[d];
            float k0=0.f,k1=0.f,k2=0.f,k3=0.f,k4=0.f,k5=0.f,k6=0.f,k7=0.f;
            for (int n = 0; n < NN; ++n) {
                const float sv = (centers[n * DD + d] - md) * il;
                const float4 pa = *(const float4*)&phiwc[n * AA];
                const float4 pb = *(const float4*)&phiwc[n * AA + 4];
                k0 += sv * pa.x; k1 += sv * pa.y; k2 += sv * pa.z; k3 += sv * pa.w;
                k4 += sv * pb.x; k5 += sv * pb.y; k6 += sv * pb.z; k7 += sv * pb.w;
            }
            K_s[d*W9+0]=k0; K_s[d*W9+1]=k1; K_s[d*W9+2]=k2; K_s[d*W9+3]=k3;
            K_s[d*W9+4]=k4; K_s[d*W9+5]=k5; K_s[d*W9+6]=k6; K_s[d*W9+7]=k7;
        }
        // cp-solve: 8 RHS, intra-wave dep on K_s (compiler emits lgkmcnt wait)
        const int aa = lw >> 3;
        float y[8];
        #pragma unroll
        for (int s = 0; s < 8; ++s) y[s] = K_s[(8 * l8 + s) * W9 + aa];
        for (int k8 = 0; k8 < 8; ++k8) {              // forward (unit-L)
            #pragma unroll
            for (int kk = 0; kk < 8; ++kk) {
                const int k = 8 * k8 + kk;
                float zk = __shfl(y[kk], (lw & 56) | k8, 64);
                #pragma unroll
                for (int s = 0; s < 8; ++s)
                    y[s] -= LmT1[k * STR + 8 * l8 + s] * zk;
            }
        }
        #pragma unroll
        for (int s = 0; s < 8; ++s) y[s] *= invd1[8 * l8 + s];
        for (int i8 = 7; i8 >= 0; --i8) {             // backward (L^T), dot-form
            #pragma unroll
            for (int ii = 7; ii >= 0; --ii) {
                const int i = 8 * i8 + ii;
                const float4 r0 = *(const float4*)&LmT1[i * STR + 8 * l8];
                const float4 r1 = *(const float4*)&LmT1[i * STR + 8 * l8 + 4];
                float part = r0.x*y[0] + r0.y*y[1] + r0.z*y[2] + r0.w*y[3]
                           + r1.x*y[4] + r1.y*y[5] + r1.z*y[6] + r1.w*y[7];
                part += __shfl_xor(part, 1, 64);
                part += __shfl_xor(part, 2, 64);
                part += __shfl_xor(part, 4, 64);
                if (l8 == i8) y[ii] -= part;
            }
        }
        #pragma unroll
        for (int s = 0; s < 8; ++s)
            cp_s[(8 * l8 + s) * W9 + aa] = y[s] * invl_s[8 * l8 + s];
    } else if (wv == 3) {
        if (lw < AA) {
            const int a = lw;
            float am = 0.f;
            for (int n = 0; n < NN; ++n) am += phiwc[n * AA + a];
            am_s[a] = am;
        }
    } else {
        // Gram pairs: 16 groups (waves 1,2) x 2 rows (n0=g, n1=g+16)
        const int g16 = (lw >> 3) + 8 * (wv - 1);
        const int n0 = g16, n1 = g16 + 16;
        float acc0[4] = {0.f,0.f,0.f,0.f}, acc1[4] = {0.f,0.f,0.f,0.f};
        const int rot = 2 * l8;
        #pragma unroll 2
        for (int e = 0; e < 16; ++e) {
            const int e4 = 4 * ((e + rot) & 15);
            const float4 hn0 = *(const float4*)&H_s[n0 * STR + e4];
            const float4 hn1 = *(const float4*)&H_s[n1 * STR + e4];
            #pragma unroll
            for (int mm = 0; mm < 4; ++mm) {
                const float4 hm = *(const float4*)&H_s[(4 * l8 + mm) * STR + e4];
                {
                    float s0 = hn0.x + hm.x, s1 = hn0.y + hm.y;
                    float s2 = hn0.z + hm.z, s3 = hn0.w + hm.w;
                    acc0[mm] += s0*s0 + s1*s1 + s2*s2 + s3*s3;
                }
                {
                    float s0 = hn1.x + hm.x, s1 = hn1.y + hm.y;
                    float s2 = hn1.z + hm.z, s3 = hn1.w + hm.w;
                    acc1[mm] += s0*s0 + s1*s1 + s2*s2 + s3*s3;
                }
            }
        }
        const float4 e1a = *(const float4*)&ws[n0 * NN + 4 * l8];
        const float4 e1b = *(const float4*)&ws[n1 * NN + 4 * l8];
        float Q0a = cq * expf(e1a.x - 0.5f * acc0[0]);
        float Q1a = cq * expf(e1a.y - 0.5f * acc0[1]);
        float Q2a = cq * expf(e1a.z - 0.5f * acc0[2]);
        float Q3a = cq * expf(e1a.w - 0.5f * acc0[3]);
        float Q0b = cq * expf(e1b.x - 0.5f * acc1[0]);
        float Q1b = cq * expf(e1b.y - 0.5f * acc1[1]);
        float Q2b = cq * expf(e1b.z - 0.5f * acc1[2]);
        float Q3b = cq * expf(e1b.w - 0.5f * acc1[3]);
        float ua[8], ub[8];
        #pragma unroll
        for (int a = 0; a < 8; ++a) {
            const float w0 = w9_s[(4*l8+0)*W9 + a], w1 = w9_s[(4*l8+1)*W9 + a];
            const float w2 = w9_s[(4*l8+2)*W9 + a], w3 = w9_s[(4*l8+3)*W9 + a];
            ua[a] = Q0a*w0 + Q1a*w1 + Q2a*w2 + Q3a*w3;
            ub[a] = Q0b*w0 + Q1b*w1 + Q2b*w2 + Q3b*w3;
            ua[a] += __shfl_xor(ua[a], 1, 64);
            ua[a] += __shfl_xor(ua[a], 2, 64);
            ua[a] += __shfl_xor(ua[a], 4, 64);
            ub[a] += __shfl_xor(ub[a], 1, 64);
            ub[a] += __shfl_xor(ub[a], 2, 64);
            ub[a] += __shfl_xor(ub[a], 4, 64);
        }
        float uva = (l8 == 0) ? ua[0] : (l8 == 1) ? ua[1] : (l8 == 2) ? ua[2] : (l8 == 3) ? ua[3]
                  : (l8 == 4) ? ua[4] : (l8 == 5) ? ua[5] : (l8 == 6) ? ua[6] : ua[7];
        float uvb = (l8 == 0) ? ub[0] : (l8 == 1) ? ub[1] : (l8 == 2) ? ub[2] : (l8 == 3) ? ub[3]
                  : (l8 == 4) ? ub[4] : (l8 == 5) ? ub[5] : (l8 == 6) ? ub[6] : ub[7];
        U_s[n0 * W9 + l8] = uva;
        U_s[n1 * W9 + l8] = uvb;
    }
    __syncthreads();

    // ---- phase C: acr = w^T U ----
    if (t < 64) {
        const int a = t >> 3, c = t & 7;
        float acc2 = 0.f;
        for (int n = 0; n < NN; ++n) acc2 += w9_s[n * W9 + a] * U_s[n * W9 + c];
        acr_s[a * W9 + c] = acc2;
    }
    __syncthreads();

    // ---- squash + outputs ----
    float* out0 = out;
    float* out1 = out + (size_t)NBATCH * AA;
    float* out2 = out + (size_t)NBATCH * AA + (size_t)NBATCH * AA * AA;
    if (t < 64) {
        const int a = t >> 3, c = t & 7;
        const float ama = am_s[a], amc = am_s[c];
        const float vac = 0.5f * (acr_s[a * W9 + c] + acr_s[c * W9 + a])
                        - ama * amc + ((a == c) ? 1e-6f : 0.0f);
        const float dca = acr_s[a * W9 + a] - ama * ama + 1e-6f;
        const float dcc = acr_s[c * W9 + c] - amc * amc + 1e-6f;
        const float q = expf(-0.5f * (dca + dcc));
        // expm1 formulation avoids catastrophic cancellation at vac ~ 1e-6
        const float sq = 0.5f * q * (expm1f(vac) * cosf(ama - amc)
                                   - expm1f(-vac) * cosf(ama + amc));
        out1[(size_t)b * 64 + t] = sq;
        if (t < AA) {
            float dct = acr_s[t * W9 + t] - am_s[t] * am_s[t] + 1e-6f;
            float e = expf(-0.5f * dct);
            out0[(size_t)b * AA + t] = e * sinf(am_s[t]);
            Ca_s[t] = e * cosf(am_s[t]);
        }
    }
    __syncthreads();
    #pragma unroll
    for (int e = 0; e < 2; ++e) {
        int idx = t + 256 * e;
        out2[(size_t)b * 512 + idx] = cp_s[(idx >> 3) * W9 + (idx & 7)] * Ca_s[idx & 7];
    }
}

extern "C" void kernel_launch(void* const* d_in, const int* in_sizes, int n_in,
                              void* d_out, int out_size, void* d_ws, size_t ws_size,
                              hipStream_t stream) {
    (void)in_sizes; (void)n_in; (void)out_size; (void)ws_size;
    const float* mean    = (const float*)d_in[0];
    const float* cov     = (const float*)d_in[1];
    const float* centers = (const float*)d_in[2];
    const float* weights = (const float*)d_in[3];
    const float* ls      = (const float*)d_in[4];
    float* ws = (float*)d_ws;
    float* o  = (float*)d_out;
    rbf_prep<<<4, 256, 0, stream>>>(centers, ls, ws);
    rbf_main<<<NBATCH, 256, 0, stream>>>(mean, cov, centers, weights, ls, ws, o);
}

// Round 10
// 214.862 us; speedup vs baseline: 2.5877x; 1.0126x over previous
//
#include <hip/hip_runtime.h>
#include <math.h>

// RBFController: B=2048, N=32 centers, D=64 dims, A=8 actions.
// One 256-thread block per batch element. Binding resource (R7/R8 model):
// per-CU LDS pipe. R10 = R8 (proven shfl factor — R9's LDS-colbuf pivot
// exchange NaN'd: same-wave predicated ds_write -> ds_read RAW inside an
// unrolled loop is NOT safe to assume at -O3; do not retry without asm
// verification) + R9's solve restructure (one wave per matrix, 4 RHS/lane:
// L rows read ONCE -> 256 ds_read_b128 in solves vs R8's 512).
// All FP sequences bitwise identical to R8 (absmax margin 1.49e-8 vs 2.03e-8).
//
// VGPR/occupancy model (measured): waves/SIMD = floor(256/VGPR_Count).
// (256,3)->cap85 -> 3 waves/SIMD; LDS 53.6KB -> 3 blocks/CU.

#define DD 64
#define NN 32
#define AA 8
#define NBATCH 2048
#define STR 68   // L^T / H row stride (words): 272 B, 16B-aligned rows
#define W9 9     // padded stride (kills stride-32-word bank hazards)

// ---------------- prep: exp1[n][m] table + logdet_lh scalar ----------------
__global__ void rbf_prep(const float* __restrict__ centers,
                         const float* __restrict__ ls,
                         float* __restrict__ ws) {
    __shared__ float cen_s[NN * DD];
    __shared__ float il2_s[DD];
    int t = threadIdx.x;
    for (int e = t; e < NN * DD; e += 256) cen_s[e] = centers[e];
    if (t < DD) { float l = ls[t]; il2_s[t] = 1.0f / (l * l); }
    __syncthreads();
    int p = blockIdx.x * 256 + t;
    if (p < NN * NN) {
        int n = p >> 5, m = p & 31;
        float acc = 0.f;
        for (int d = 0; d < DD; ++d) {
            float df = cen_s[n * DD + d] - cen_s[m * DD + d];
            acc += df * df * il2_s[d];
        }
        ws[p] = -0.25f * acc;              // exp1[n][m]
    }
    if (blockIdx.x == 0 && t < DD) {
        float l = ls[t];
        float v = logf(0.5f * l * l);
        #pragma unroll
        for (int o = 1; o < 64; o <<= 1) v += __shfl_xor(v, o, 64);
        if (t == 0) ws[NN * NN] = v;       // logdet_lh
    }
}

// Wave-local panel factorization (PROVEN shfl version). PRECONDITION:
// executing wave owns cols 16p..16p+15 of A (lane lw: rows 4*(lw&15)..,
// panel-local col tile lw>>4).
__device__ __forceinline__ void factor_panel(float (&A)[4][4], const int p,
    float* __restrict__ LmT, float* __restrict__ diag_s, float* __restrict__ invd_s,
    const int lw)
{
    const int rb  = lw & 15;
    const int cbl = lw >> 4;
    const int c0  = 16 * p + 4 * cbl;
    const int r0  = 4 * rb;
    #pragma unroll
    for (int jj = 0; jj < 16; ++jj) {
        const int q  = jj >> 2;
        const int ci = jj & 3;
        const int j  = 16 * p + jj;
        const int fsrc = rb | (q << 4);
        const int hsrc = (4 * p + cbl) | (q << 4);
        const int dsrc = (4 * p + q) | (q << 4);
        float d  = __shfl(A[ci][ci], dsrc, 64);
        float f0 = __shfl(A[0][ci], fsrc, 64);
        float f1 = __shfl(A[1][ci], fsrc, 64);
        float f2 = __shfl(A[2][ci], fsrc, 64);
        float f3 = __shfl(A[3][ci], fsrc, 64);
        float h0 = __shfl(A[0][ci], hsrc, 64);
        float h1 = __shfl(A[1][ci], hsrc, 64);
        float h2 = __shfl(A[2][ci], hsrc, 64);
        float h3 = __shfl(A[3][ci], hsrc, 64);
        float id = __builtin_amdgcn_rcpf(d);   // cond(A) ~ 1; ~1ulp fine
        float fr[4];
        fr[0] = (r0 + 0 > j) ? f0 : 0.f;
        fr[1] = (r0 + 1 > j) ? f1 : 0.f;
        fr[2] = (r0 + 2 > j) ? f2 : 0.f;
        fr[3] = (r0 + 3 > j) ? f3 : 0.f;
        float hc[4];
        hc[0] = (c0 + 0 > j) ? h0 * id : 0.f;
        hc[1] = (c0 + 1 > j) ? h1 * id : 0.f;
        hc[2] = (c0 + 2 > j) ? h2 * id : 0.f;
        hc[3] = (c0 + 3 > j) ? h3 * id : 0.f;
        #pragma unroll
        for (int s = 0; s < 4; ++s)
            #pragma unroll
            for (int c = 0; c < 4; ++c)
                A[s][c] -= fr[s] * hc[c];
        if (cbl == 0) {
            float4 v = make_float4(fr[0] * id, fr[1] * id, fr[2] * id, fr[3] * id);
            *(float4*)&LmT[j * STR + r0] = v;
        }
        if (lw == jj) { diag_s[j] = d; invd_s[j] = id; }
    }
}

// Rank-16 trailing update, single matrix. Zero-filled L^T rows auto-mask <=k.
__device__ __forceinline__ void trailing_one(float (&A)[4][4], const int p,
    const float* __restrict__ LmT, const float* __restrict__ diag_s,
    const int rb, const int cbX)
{
    #pragma unroll 2
    for (int kk = 0; kk < 16; ++kk) {
        const int k = 16 * p + kk;
        const float4 Lr = *(const float4*)&LmT[k * STR + 4 * rb];
        const float4 Lc = *(const float4*)&LmT[k * STR + 4 * cbX];
        const float dk = diag_s[k];
        const float h0 = Lc.x * dk, h1 = Lc.y * dk, h2 = Lc.z * dk, h3 = Lc.w * dk;
        A[0][0] -= Lr.x * h0; A[0][1] -= Lr.x * h1; A[0][2] -= Lr.x * h2; A[0][3] -= Lr.x * h3;
        A[1][0] -= Lr.y * h0; A[1][1] -= Lr.y * h1; A[1][2] -= Lr.y * h2; A[1][3] -= Lr.y * h3;
        A[2][0] -= Lr.z * h0; A[2][1] -= Lr.z * h1; A[2][2] -= Lr.z * h2; A[2][3] -= Lr.z * h3;
        A[3][0] -= Lr.w * h0; A[3][1] -= Lr.w * h1; A[3][2] -= Lr.w * h2; A[3][3] -= Lr.w * h3;
    }
}

__global__ __launch_bounds__(256, 3) void rbf_main(
    const float* __restrict__ mean,      // (B,64)
    const float* __restrict__ cov,       // (B,64,64)
    const float* __restrict__ centers,   // (32,64)
    const float* __restrict__ weights,   // (32,8)
    const float* __restrict__ ls,        // (64,)
    const float* __restrict__ ws,        // exp1[1024], logdet_lh at [1024]
    float* __restrict__ out)
{
    __shared__ __align__(16) float LmT1[DD * STR];  // 17408 B  L1^T (M1)
    __shared__ __align__(16) float LmT2[DD * STR];  // 17408 B  L2^T (M2)
    __shared__ __align__(16) float H_s[NN * STR];   // 8704 B
    __shared__ __align__(16) float K_s[DD * W9];    // 2304 B
    __shared__ __align__(16) float cp_s[DD * W9];   // 2304 B
    __shared__ __align__(16) float phiwc[NN * AA];  // 1024 B compact (b128 reads)
    __shared__ float diag1[DD], invd1[DD], diag2[DD], invd2[DD];
    __shared__ float mean_s[DD], invl_s[DD], l2h_s[DD];
    __shared__ float w9_s[NN * W9], U_s[NN * W9];
    __shared__ float am_s[AA], acr_s[AA * W9], Ca_s[AA];
    __shared__ float ldlh_s;
    // total ~53.6 KB -> 3 blocks/CU

    const int t   = threadIdx.x;
    const int b   = blockIdx.x;
    const int lw  = t & 63;
    const int wv  = t >> 6;
    const int rb  = t & 15;            // row tile (rows 4rb..4rb+3), both matrices
    const int cb  = t >> 4;            // M2 col tile; wave w owns M2 cols 16w..16w+15
    const int cb1 = (cb + 8) & 15;     // M1 col tile; wave w owns M1 panel (w+2)&3
    const int wp1 = (wv + 2) & 3;      // M1 panel owned by this wave
    const int l8  = t & 7;             // lane-in-group (rows 8*l8..8*l8+7)
    const float* cvb = cov + (size_t)b * DD * DD;

    // ---- stage small arrays ----
    if (t < DD) {
        float l = ls[t];
        invl_s[t] = 1.0f / l;
        l2h_s[t]  = 0.5f * l * l;
        mean_s[t] = mean[(size_t)b * DD + t];
    }
    w9_s[(t >> 3) * W9 + (t & 7)] = weights[t];
    if (t == 0) ldlh_s = ws[NN * NN];
    __syncthreads();

    // ---- build tiles: A2 at (4rb, 4cb), A1 at (4rb, 4cb1) — symmetric loads
    float A1[4][4], A2[4][4];
    {
        #pragma unroll
        for (int c = 0; c < 4; ++c) {
            const int gr = 4 * cb + c;
            const float4 cv = *(const float4*)(cvb + (size_t)gr * DD + 4 * rb);
            A2[0][c] = cv.x + ((4*rb+0 == gr) ? l2h_s[gr] : 0.0f);
            A2[1][c] = cv.y + ((4*rb+1 == gr) ? l2h_s[gr] : 0.0f);
            A2[2][c] = cv.z + ((4*rb+2 == gr) ? l2h_s[gr] : 0.0f);
            A2[3][c] = cv.w + ((4*rb+3 == gr) ? l2h_s[gr] : 0.0f);
        }
        const float il0 = invl_s[4*rb+0], il1 = invl_s[4*rb+1],
                    il2 = invl_s[4*rb+2], il3 = invl_s[4*rb+3];
        #pragma unroll
        for (int c = 0; c < 4; ++c) {
            const int gr = 4 * cb1 + c;
            const float4 cv = *(const float4*)(cvb + (size_t)gr * DD + 4 * rb);
            const float ilc = invl_s[gr];
            A1[0][c] = cv.x * il0 * ilc + ((4*rb+0 == gr) ? 1.0f : 0.0f);
            A1[1][c] = cv.y * il1 * ilc + ((4*rb+1 == gr) ? 1.0f : 0.0f);
            A1[2][c] = cv.z * il2 * ilc + ((4*rb+2 == gr) ? 1.0f : 0.0f);
            A1[3][c] = cv.w * il3 * ilc + ((4*rb+3 == gr) ? 1.0f : 0.0f);
        }
    }

    // ---- FUSED factorization with wave-uniform trailing skip ----
    if (wv == 0) factor_panel(A2, 0, LmT2, diag2, invd2, lw);
    if (wv == 2) factor_panel(A1, 0, LmT1, diag1, invd1, lw);
    #pragma unroll 1
    for (int p = 0; p < 3; ++p) {
        __syncthreads();
        if (wv  >= p + 1) trailing_one(A2, p, LmT2, diag2, rb, cb);
        if (wp1 >= p + 1) trailing_one(A1, p, LmT1, diag1, rb, cb1);
        if (wv == p + 1)         factor_panel(A2, p + 1, LmT2, diag2, invd2, lw);
        if (wv == ((p + 3) & 3)) factor_panel(A1, p + 1, LmT1, diag1, invd1, lw);
    }
    __syncthreads();

    // ---- per-wave logdets (redundant; no barrier needed) ----
    float logdet1, cq;
    {
        float v1 = logf(diag1[lw]);
        float v2 = logf(diag2[lw]);
        #pragma unroll
        for (int o = 1; o < 64; o <<= 1) {
            v1 += __shfl_xor(v1, o, 64);
            v2 += __shfl_xor(v2, o, 64);
        }
        logdet1 = v1;
        cq = expf(0.5f * (ldlh_s - v2));
    }

    // ---- phase S: wave0 = M1 solve (32 RHS, 4/lane); wave1 = M2 solve ----
    // L rows are read ONCE per matrix; 4 RHS share every b128.
    if (wv == 0) {
        const int gr8 = lw >> 3;   // RHS n = gr8 + 8*rr
        float x0[8], x1v[8], x2v[8], x3v[8];
        #pragma unroll
        for (int rr = 0; rr < 4; ++rr) {
            const int n = gr8 + 8 * rr;
            const float4 ca = *(const float4*)(centers + n * DD + 8 * l8);
            const float4 cz = *(const float4*)(centers + n * DD + 8 * l8 + 4);
            float da[8] = {ca.x,ca.y,ca.z,ca.w,cz.x,cz.y,cz.z,cz.w};
            float* xp = (rr == 0) ? x0 : (rr == 1) ? x1v : (rr == 2) ? x2v : x3v;
            #pragma unroll
            for (int s = 0; s < 8; ++s) {
                const int i = 8 * l8 + s;
                xp[s] = (da[s] - mean_s[i]) * invl_s[i];
            }
        }
        for (int k8 = 0; k8 < 8; ++k8) {
            #pragma unroll
            for (int kk = 0; kk < 8; ++kk) {
                const int k = 8 * k8 + kk;
                const int src = (lw & 56) | k8;
                float z0 = __shfl(x0[kk],  src, 64);
                float z1 = __shfl(x1v[kk], src, 64);
                float z2 = __shfl(x2v[kk], src, 64);
                float z3 = __shfl(x3v[kk], src, 64);
                const float4 LA = *(const float4*)&LmT1[k * STR + 8 * l8];
                const float4 LB = *(const float4*)&LmT1[k * STR + 8 * l8 + 4];
                float l1[8] = {LA.x,LA.y,LA.z,LA.w,LB.x,LB.y,LB.z,LB.w};
                #pragma unroll
                for (int s = 0; s < 8; ++s) {
                    x0[s]  -= l1[s] * z0;
                    x1v[s] -= l1[s] * z1;
                    x2v[s] -= l1[s] * z2;
                    x3v[s] -= l1[s] * z3;
                }
            }
        }
        #pragma unroll
        for (int rr = 0; rr < 4; ++rr) {
            const int n = gr8 + 8 * rr;
            const float* xp = (rr == 0) ? x0 : (rr == 1) ? x1v : (rr == 2) ? x2v : x3v;
            float qf = 0.f;
            #pragma unroll
            for (int s = 0; s < 8; ++s) qf += xp[s] * xp[s] * invd1[8 * l8 + s];
            qf += __shfl_xor(qf, 1, 64);
            qf += __shfl_xor(qf, 2, 64);
            qf += __shfl_xor(qf, 4, 64);
            float ph = expf(-0.5f * (logdet1 + qf));
            phiwc[n * AA + l8] = ph * w9_s[n * W9 + l8];
        }
    } else if (wv == 1) {
        const int gr8 = lw >> 3;
        float x0[8], x1v[8], x2v[8], x3v[8];
        #pragma unroll
        for (int rr = 0; rr < 4; ++rr) {
            const int n = gr8 + 8 * rr;
            const float4 ca = *(const float4*)(centers + n * DD + 8 * l8);
            const float4 cz = *(const float4*)(centers + n * DD + 8 * l8 + 4);
            float da[8] = {ca.x,ca.y,ca.z,ca.w,cz.x,cz.y,cz.z,cz.w};
            float* xp = (rr == 0) ? x0 : (rr == 1) ? x1v : (rr == 2) ? x2v : x3v;
            #pragma unroll
            for (int s = 0; s < 8; ++s) {
                const int i = 8 * l8 + s;
                xp[s] = 0.5f * (da[s] - mean_s[i]);
            }
        }
        for (int k8 = 0; k8 < 8; ++k8) {
            #pragma unroll
            for (int kk = 0; kk < 8; ++kk) {
                const int k = 8 * k8 + kk;
                const int src = (lw & 56) | k8;
                float z0 = __shfl(x0[kk],  src, 64);
                float z1 = __shfl(x1v[kk], src, 64);
                float z2 = __shfl(x2v[kk], src, 64);
                float z3 = __shfl(x3v[kk], src, 64);
                const float4 MA = *(const float4*)&LmT2[k * STR + 8 * l8];
                const float4 MB = *(const float4*)&LmT2[k * STR + 8 * l8 + 4];
                float l2[8] = {MA.x,MA.y,MA.z,MA.w,MB.x,MB.y,MB.z,MB.w};
                #pragma unroll
                for (int s = 0; s < 8; ++s) {
                    x0[s]  -= l2[s] * z0;
                    x1v[s] -= l2[s] * z1;
                    x2v[s] -= l2[s] * z2;
                    x3v[s] -= l2[s] * z3;
                }
            }
        }
        #pragma unroll
        for (int rr = 0; rr < 4; ++rr) {
            const int n = gr8 + 8 * rr;
            const float* xp = (rr == 0) ? x0 : (rr == 1) ? x1v : (rr == 2) ? x2v : x3v;
            float h[8];
            #pragma unroll
            for (int s = 0; s < 8; ++s) h[s] = xp[s] * sqrtf(invd2[8 * l8 + s]);
            *(float4*)&H_s[n * STR + 8 * l8]     = make_float4(h[0],h[1],h[2],h[3]);
            *(float4*)&H_s[n * STR + 8 * l8 + 4] = make_float4(h[4],h[5],h[6],h[7]);
        }
    }
    __syncthreads();

    // ---- phase T: wave0 K-build + cp-solve | waves1,2 Gram pairs | wave3 amean
    if (wv == 0) {
        {   // K[d][a] = sum_n s_n[d] * phiw[n][a]; d = lane, all 8 a
            const int d = lw;
            const float md = mean_s[d], il = invl_s[d];
            float k0=0.f,k1=0.f,k2=0.f,k3=0.f,k4=0.f,k5=0.f,k6=0.f,k7=0.f;
            for (int n = 0; n < NN; ++n) {
                const float sv = (centers[n * DD + d] - md) * il;
                const float4 pa = *(const float4*)&phiwc[n * AA];
                const float4 pb = *(const float4*)&phiwc[n * AA + 4];
                k0 += sv * pa.x; k1 += sv * pa.y; k2 += sv * pa.z; k3 += sv * pa.w;
                k4 += sv * pb.x; k5 += sv * pb.y; k6 += sv * pb.z; k7 += sv * pb.w;
            }
            K_s[d*W9+0]=k0; K_s[d*W9+1]=k1; K_s[d*W9+2]=k2; K_s[d*W9+3]=k3;
            K_s[d*W9+4]=k4; K_s[d*W9+5]=k5; K_s[d*W9+6]=k6; K_s[d*W9+7]=k7;
        }
        // cp-solve: 8 RHS, intra-wave dep on K_s
        const int aa = lw >> 3;
        float y[8];
        #pragma unroll
        for (int s = 0; s < 8; ++s) y[s] = K_s[(8 * l8 + s) * W9 + aa];
        for (int k8 = 0; k8 < 8; ++k8) {              // forward (unit-L)
            #pragma unroll
            for (int kk = 0; kk < 8; ++kk) {
                const int k = 8 * k8 + kk;
                float zk = __shfl(y[kk], (lw & 56) | k8, 64);
                #pragma unroll
                for (int s = 0; s < 8; ++s)
                    y[s] -= LmT1[k * STR + 8 * l8 + s] * zk;
            }
        }
        #pragma unroll
        for (int s = 0; s < 8; ++s) y[s] *= invd1[8 * l8 + s];
        for (int i8 = 7; i8 >= 0; --i8) {             // backward (L^T), dot-form
            #pragma unroll
            for (int ii = 7; ii >= 0; --ii) {
                const int i = 8 * i8 + ii;
                const float4 r0 = *(const float4*)&LmT1[i * STR + 8 * l8];
                const float4 r1 = *(const float4*)&LmT1[i * STR + 8 * l8 + 4];
                float part = r0.x*y[0] + r0.y*y[1] + r0.z*y[2] + r0.w*y[3]
                           + r1.x*y[4] + r1.y*y[5] + r1.z*y[6] + r1.w*y[7];
                part += __shfl_xor(part, 1, 64);
                part += __shfl_xor(part, 2, 64);
                part += __shfl_xor(part, 4, 64);
                if (l8 == i8) y[ii] -= part;
            }
        }
        #pragma unroll
        for (int s = 0; s < 8; ++s)
            cp_s[(8 * l8 + s) * W9 + aa] = y[s] * invl_s[8 * l8 + s];
    } else if (wv == 3) {
        if (lw < AA) {
            const int a = lw;
            float am = 0.f;
            for (int n = 0; n < NN; ++n) am += phiwc[n * AA + a];
            am_s[a] = am;
        }
    } else {
        // Gram pairs: 16 groups (waves 1,2) x 2 rows (n0=g, n1=g+16)
        const int g16 = (lw >> 3) + 8 * (wv - 1);
        const int n0 = g16, n1 = g16 + 16;
        float acc0[4] = {0.f,0.f,0.f,0.f}, acc1[4] = {0.f,0.f,0.f,0.f};
        const int rot = 2 * l8;
        #pragma unroll 2
        for (int e = 0; e < 16; ++e) {
            const int e4 = 4 * ((e + rot) & 15);
            const float4 hn0 = *(const float4*)&H_s[n0 * STR + e4];
            const float4 hn1 = *(const float4*)&H_s[n1 * STR + e4];
            #pragma unroll
            for (int mm = 0; mm < 4; ++mm) {
                const float4 hm = *(const float4*)&H_s[(4 * l8 + mm) * STR + e4];
                {
                    float s0 = hn0.x + hm.x, s1 = hn0.y + hm.y;
                    float s2 = hn0.z + hm.z, s3 = hn0.w + hm.w;
                    acc0[mm] += s0*s0 + s1*s1 + s2*s2 + s3*s3;
                }
                {
                    float s0 = hn1.x + hm.x, s1 = hn1.y + hm.y;
                    float s2 = hn1.z + hm.z, s3 = hn1.w + hm.w;
                    acc1[mm] += s0*s0 + s1*s1 + s2*s2 + s3*s3;
                }
            }
        }
        const float4 e1a = *(const float4*)&ws[n0 * NN + 4 * l8];
        const float4 e1b = *(const float4*)&ws[n1 * NN + 4 * l8];
        float Q0a = cq * expf(e1a.x - 0.5f * acc0[0]);
        float Q1a = cq * expf(e1a.y - 0.5f * acc0[1]);
        float Q2a = cq * expf(e1a.z - 0.5f * acc0[2]);
        float Q3a = cq * expf(e1a.w - 0.5f * acc0[3]);
        float Q0b = cq * expf(e1b.x - 0.5f * acc1[0]);
        float Q1b = cq * expf(e1b.y - 0.5f * acc1[1]);
        float Q2b = cq * expf(e1b.z - 0.5f * acc1[2]);
        float Q3b = cq * expf(e1b.w - 0.5f * acc1[3]);
        float ua[8], ub[8];
        #pragma unroll
        for (int a = 0; a < 8; ++a) {
            const float w0 = w9_s[(4*l8+0)*W9 + a], w1 = w9_s[(4*l8+1)*W9 + a];
            const float w2 = w9_s[(4*l8+2)*W9 + a], w3 = w9_s[(4*l8+3)*W9 + a];
            ua[a] = Q0a*w0 + Q1a*w1 + Q2a*w2 + Q3a*w3;
            ub[a] = Q0b*w0 + Q1b*w1 + Q2b*w2 + Q3b*w3;
            ua[a] += __shfl_xor(ua[a], 1, 64);
            ua[a] += __shfl_xor(ua[a], 2, 64);
            ua[a] += __shfl_xor(ua[a], 4, 64);
            ub[a] += __shfl_xor(ub[a], 1, 64);
            ub[a] += __shfl_xor(ub[a], 2, 64);
            ub[a] += __shfl_xor(ub[a], 4, 64);
        }
        float uva = (l8 == 0) ? ua[0] : (l8 == 1) ? ua[1] : (l8 == 2) ? ua[2] : (l8 == 3) ? ua[3]
                  : (l8 == 4) ? ua[4] : (l8 == 5) ? ua[5] : (l8 == 6) ? ua[6] : ua[7];
        float uvb = (l8 == 0) ? ub[0] : (l8 == 1) ? ub[1] : (l8 == 2) ? ub[2] : (l8 == 3) ? ub[3]
                  : (l8 == 4) ? ub[4] : (l8 == 5) ? ub[5] : (l8 == 6) ? ub[6] : ub[7];
        U_s[n0 * W9 + l8] = uva;
        U_s[n1 * W9 + l8] = uvb;
    }
    __syncthreads();

    // ---- phase C: acr = w^T U ----
    if (t < 64) {
        const int a = t >> 3, c = t & 7;
        float acc2 = 0.f;
        for (int n = 0; n < NN; ++n) acc2 += w9_s[n * W9 + a] * U_s[n * W9 + c];
        acr_s[a * W9 + c] = acc2;
    }
    __syncthreads();

    // ---- squash + outputs ----
    float* out0 = out;
    float* out1 = out + (size_t)NBATCH * AA;
    float* out2 = out + (size_t)NBATCH * AA + (size_t)NBATCH * AA * AA;
    if (t < 64) {
        const int a = t >> 3, c = t & 7;
        const float ama = am_s[a], amc = am_s[c];
        const float vac = 0.5f * (acr_s[a * W9 + c] + acr_s[c * W9 + a])
                        - ama * amc + ((a == c) ? 1e-6f : 0.0f);
        const float dca = acr_s[a * W9 + a] - ama * ama + 1e-6f;
        const float dcc = acr_s[c * W9 + c] - amc * amc + 1e-6f;
        const float q = expf(-0.5f * (dca + dcc));
        // expm1 formulation avoids catastrophic cancellation at vac ~ 1e-6
        const float sq = 0.5f * q * (expm1f(vac) * cosf(ama - amc)
                                   - expm1f(-vac) * cosf(ama + amc));
        out1[(size_t)b * 64 + t] = sq;
        if (t < AA) {
            float dct = acr_s[t * W9 + t] - am_s[t] * am_s[t] + 1e-6f;
            float e = expf(-0.5f * dct);
            out0[(size_t)b * AA + t] = e * sinf(am_s[t]);
            Ca_s[t] = e * cosf(am_s[t]);
        }
    }
    __syncthreads();
    #pragma unroll
    for (int e = 0; e < 2; ++e) {
        int idx = t + 256 * e;
        out2[(size_t)b * 512 + idx] = cp_s[(idx >> 3) * W9 + (idx & 7)] * Ca_s[idx & 7];
    }
}

extern "C" void kernel_launch(void* const* d_in, const int* in_sizes, int n_in,
                              void* d_out, int out_size, void* d_ws, size_t ws_size,
                              hipStream_t stream) {
    (void)in_sizes; (void)n_in; (void)out_size; (void)ws_size;
    const float* mean    = (const float*)d_in[0];
    const float* cov     = (const float*)d_in[1];
    const float* centers = (const float*)d_in[2];
    const float* weights = (const float*)d_in[3];
    const float* ls      = (const float*)d_in[4];
    float* ws = (float*)d_ws;
    float* o  = (float*)d_out;
    rbf_prep<<<4, 256, 0, stream>>>(centers, ls, ws);
    rbf_main<<<NBATCH, 256, 0, stream>>>(mean, cov, centers, weights, ls, ws, o);
}